// Round 2
// baseline (720.689 us; speedup 1.0000x reference)
//
#include <hip/hip_runtime.h>
#include <math.h>

#define BDIM 4096
#define DDIM 256
#define NSTATE 9000000

#define C_ALPHA 0.5f
#define C_GAMMA_S 0.8f
#define C_GAMMA_U 0.9f
#define C_RHO 6.0f
#define C_EPS 1e-14f
#define C_ETA 0.01f
#define C_TAU_MIN 0.001f
#define C_TAU_MAX 1.0f
#define C_GRAD_CLIP 5.0f

// ---------- order-preserving float<->uint encoding for atomicMax ----------
__device__ inline unsigned encf(float f) {
    unsigned u = __float_as_uint(f);
    return (u & 0x80000000u) ? ~u : (u | 0x80000000u);
}
__device__ inline float decf(unsigned e) {
    return (e & 0x80000000u) ? __uint_as_float(e ^ 0x80000000u)
                             : __uint_as_float(~e);
}
// note: memset-0 init is safe: every encoding of a real float is > 0x007FFFFF >= 0.

// ---------- K0: inverse norms of zis (rows 0..B-1) and zjs (rows B..2B-1) ----------
__global__ __launch_bounds__(256) void kinv(const float* __restrict__ zis,
                                            const float* __restrict__ zjs,
                                            float* __restrict__ invnI,
                                            float* __restrict__ invnJ) {
    int row = blockIdx.x;
    int t = threadIdx.x;   // 256 == DDIM
    const float* src = (row < BDIM) ? zis + (size_t)row * DDIM
                                    : zjs + (size_t)(row - BDIM) * DDIM;
    float v = src[t];
    __shared__ float red[256];
    red[t] = v * v;
    __syncthreads();
    for (int s = 128; s > 0; s >>= 1) {
        if (t < s) red[t] += red[t + s];
        __syncthreads();
    }
    if (t == 0) {
        float inv = rsqrtf(red[0]);
        if (row < BDIM) invnI[row] = inv; else invnJ[row - BDIM] = inv;
    }
}

// ---------- fused GEMM passes (sim never materialized) ----------
// MODE 0: row/col max + diag.   MODE 1: exp-sum reductions.
// Blocks with bid%3==0 are copy blocks (4 state banks -> output).
#define BMT 128
#define BNT 128
#define BKT 16

__device__ inline int rowIdxOf(int ty, int mi) { return ty * 4 + (mi & 3) + ((mi >> 2) << 6); }
__device__ inline int colIdxOf(int tx, int ni) { return tx * 4 + (ni & 3) + ((ni >> 2) << 6); }

template <int MODE>
__global__ __launch_bounds__(256) void kpass(
    const float* __restrict__ ZA, const float* __restrict__ ZB,
    const float* __restrict__ invA, const float* __restrict__ invB,
    unsigned* __restrict__ rowmaxE, unsigned* __restrict__ colmaxE,
    float* __restrict__ diag,
    const float* __restrict__ rowBv, const float* __restrict__ rowIT,
    const float* __restrict__ colBv, const float* __restrict__ colIT,
    float* __restrict__ gRowA, float* __restrict__ gRowC,
    float* __restrict__ gColA, float* __restrict__ gColC,
    const float* __restrict__ cp0, const float* __restrict__ cp1,
    const float* __restrict__ cp2, const float* __restrict__ cp3,
    float* __restrict__ cpo)
{
    __shared__ float As[BKT][BMT + 4];
    __shared__ float Bs[BKT][BNT + 4];
    __shared__ float epiF[512];

    int bid = blockIdx.x;
    int t = threadIdx.x;

    if (bid % 3 == 0) {
        // ---- copy role: 512 blocks stream 4 state banks to output ----
        long base = (long)(bid / 3) * 256 + t;
        const float* srcs[4] = {cp0, cp1, cp2, cp3};
#pragma unroll
        for (int b = 0; b < 4; b++) {
            const float* s = srcs[b];
            float* d = cpo + (long)b * NSTATE;
#pragma unroll 4
            for (long k = base; k < NSTATE; k += 131072) d[k] = s[k];
        }
        return;
    }

    // ---- GEMM role ----
    int gid = (bid / 3) * 2 + (bid % 3) - 1;   // 0..1023
    int by = gid >> 5, bx = gid & 31;
    int tx = t & 15, ty = t >> 4;
    int m0 = by * BMT, n0 = bx * BNT;
    int kq = (t & 3) * 4;   // 0,4,8,12
    int lrow = t >> 2;      // 0..63

    float ivA0 = invA[m0 + lrow], ivA1 = invA[m0 + lrow + 64];
    float ivB0 = invB[n0 + lrow], ivB1 = invB[n0 + lrow + 64];

    float acc[8][8];
#pragma unroll
    for (int a = 0; a < 8; a++)
#pragma unroll
        for (int b = 0; b < 8; b++) acc[a][b] = 0.f;

    for (int k0 = 0; k0 < DDIM; k0 += BKT) {
        float4 a0 = *(const float4*)&ZA[(size_t)(m0 + lrow) * DDIM + k0 + kq];
        float4 a1 = *(const float4*)&ZA[(size_t)(m0 + lrow + 64) * DDIM + k0 + kq];
        float4 b0 = *(const float4*)&ZB[(size_t)(n0 + lrow) * DDIM + k0 + kq];
        float4 b1 = *(const float4*)&ZB[(size_t)(n0 + lrow + 64) * DDIM + k0 + kq];
        a0.x *= ivA0; a0.y *= ivA0; a0.z *= ivA0; a0.w *= ivA0;
        a1.x *= ivA1; a1.y *= ivA1; a1.z *= ivA1; a1.w *= ivA1;
        b0.x *= ivB0; b0.y *= ivB0; b0.z *= ivB0; b0.w *= ivB0;
        b1.x *= ivB1; b1.y *= ivB1; b1.z *= ivB1; b1.w *= ivB1;
        __syncthreads();
        As[kq + 0][lrow] = a0.x; As[kq + 1][lrow] = a0.y; As[kq + 2][lrow] = a0.z; As[kq + 3][lrow] = a0.w;
        As[kq + 0][lrow + 64] = a1.x; As[kq + 1][lrow + 64] = a1.y; As[kq + 2][lrow + 64] = a1.z; As[kq + 3][lrow + 64] = a1.w;
        Bs[kq + 0][lrow] = b0.x; Bs[kq + 1][lrow] = b0.y; Bs[kq + 2][lrow] = b0.z; Bs[kq + 3][lrow] = b0.w;
        Bs[kq + 0][lrow + 64] = b1.x; Bs[kq + 1][lrow + 64] = b1.y; Bs[kq + 2][lrow + 64] = b1.z; Bs[kq + 3][lrow + 64] = b1.w;
        __syncthreads();
#pragma unroll
        for (int k = 0; k < BKT; k++) {
            float4 t0 = *(const float4*)&As[k][ty * 4];
            float4 t1 = *(const float4*)&As[k][ty * 4 + 64];
            float4 t2 = *(const float4*)&Bs[k][tx * 4];
            float4 t3 = *(const float4*)&Bs[k][tx * 4 + 64];
            float am[8] = {t0.x, t0.y, t0.z, t0.w, t1.x, t1.y, t1.z, t1.w};
            float bn[8] = {t2.x, t2.y, t2.z, t2.w, t3.x, t3.y, t3.z, t3.w};
#pragma unroll
            for (int mi = 0; mi < 8; mi++)
#pragma unroll
                for (int ni = 0; ni < 8; ni++)
                    acc[mi][ni] = fmaf(am[mi], bn[ni], acc[mi][ni]);
        }
    }

    if (MODE == 0) {
        // ---- epilogue: per-row / per-col maxima + diag ----
        unsigned* epiU = (unsigned*)epiF;   // [0..127] rowmax, [128..255] colmax
        __syncthreads();
        epiU[t] = 0u;          // valid -inf under encf ordering
        if (t < 256 - 0) {}    // all 256 entries covered
        __syncthreads();
#pragma unroll
        for (int mi = 0; mi < 8; mi++) {
            float m = acc[mi][0];
#pragma unroll
            for (int ni = 1; ni < 8; ni++) m = fmaxf(m, acc[mi][ni]);
            atomicMax(&epiU[rowIdxOf(ty, mi)], encf(m));
        }
#pragma unroll
        for (int ni = 0; ni < 8; ni++) {
            float m = acc[0][ni];
#pragma unroll
            for (int mi = 1; mi < 8; mi++) m = fmaxf(m, acc[mi][ni]);
            atomicMax(&epiU[128 + colIdxOf(tx, ni)], encf(m));
        }
        __syncthreads();
        if (t < 128) atomicMax(&rowmaxE[m0 + t], epiU[t]);
        else         atomicMax(&colmaxE[n0 + (t - 128)], epiU[t]);
        if (bx == by) {
#pragma unroll
            for (int mi = 0; mi < 8; mi++) {
                int r = rowIdxOf(ty, mi);
#pragma unroll
                for (int ni = 0; ni < 8; ni++) {
                    if (r == colIdxOf(tx, ni)) diag[m0 + r] = acc[mi][ni];
                }
            }
        }
    } else {
        // ---- epilogue: exp sums per row and per col ----
        __syncthreads();
        epiF[t] = 0.f; epiF[t + 256] = 0.f;   // rowA,rowC,colA,colC (128 each)
        __syncthreads();
        float dR[8], bR[8], iR[8], rA[8], rC[8];
#pragma unroll
        for (int mi = 0; mi < 8; mi++) {
            int r = m0 + rowIdxOf(ty, mi);
            dR[mi] = diag[r]; bR[mi] = rowBv[r]; iR[mi] = rowIT[r];
            rA[mi] = 0.f; rC[mi] = 0.f;
        }
#pragma unroll
        for (int ni = 0; ni < 8; ni++) {
            int cl = colIdxOf(tx, ni);
            int c = n0 + cl;
            float dgc = diag[c], bc = colBv[c], ic = colIT[c];
            float cA = 0.f, cC = 0.f;
#pragma unroll
            for (int mi = 0; mi < 8; mi++) {
                int r = m0 + rowIdxOf(ty, mi);
                float s = acc[mi][ni];
                bool dia = (r == c);
                float dr = s - dR[mi];
                float er = dia ? 0.f : __expf(dr * iR[mi] - bR[mi]);
                rA[mi] += er; rC[mi] += er * dr;
                float dc = s - dgc;
                float et = dia ? 0.f : __expf(dc * ic - bc);
                cA += et; cC += et * dc;
            }
            atomicAdd(&epiF[256 + cl], cA);
            atomicAdd(&epiF[384 + cl], cC);
        }
#pragma unroll
        for (int mi = 0; mi < 8; mi++) {
            int rl = rowIdxOf(ty, mi);
            atomicAdd(&epiF[rl], rA[mi]);
            atomicAdd(&epiF[128 + rl], rC[mi]);
        }
        __syncthreads();
        if (t < 128) {
            atomicAdd(&gRowA[m0 + t], epiF[t]);
            atomicAdd(&gRowC[m0 + t], epiF[128 + t]);
        } else {
            int c = t - 128;
            atomicAdd(&gColA[n0 + c], epiF[256 + c]);
            atomicAdd(&gColC[n0 + c], epiF[384 + c]);
        }
    }
}

// ---------- K-mid: per-row/col shifted max -> b_new, 1/tau ----------
__global__ __launch_bounds__(256) void kmid(const unsigned* __restrict__ rowmaxE,
                                            const unsigned* __restrict__ colmaxE,
                                            const float* __restrict__ diag,
                                            const int* __restrict__ ids,
                                            const float* __restrict__ b_I,
                                            const float* __restrict__ tau_I,
                                            const float* __restrict__ b_T,
                                            const float* __restrict__ tau_T,
                                            float* __restrict__ rowBv, float* __restrict__ rowIT,
                                            float* __restrict__ colBv, float* __restrict__ colIT) {
    int i = blockIdx.x * 256 + threadIdx.x;
    if (i >= BDIM) return;
    int id = ids[i];
    float dg = diag[i];
    float tau = tau_I[id];
    float nb = fmaxf(b_I[id], (decf(rowmaxE[i]) - dg) / tau);
    rowBv[i] = nb; rowIT[i] = 1.0f / tau;
    float taut = tau_T[id];
    float nbt = fmaxf(b_T[id], (decf(colmaxE[i]) - dg) / taut);
    colBv[i] = nbt; colIT[i] = 1.0f / taut;
}

// ---------- K-final: per-row and per-col state update + outputs ----------
__global__ __launch_bounds__(256) void kfinal2(const int* __restrict__ ids,
                                               const float* __restrict__ s_I, const float* __restrict__ b_I,
                                               const float* __restrict__ u_I, const float* __restrict__ tau_I,
                                               const float* __restrict__ s_T, const float* __restrict__ b_T,
                                               const float* __restrict__ u_T, const float* __restrict__ tau_T,
                                               const float* __restrict__ rowBv, const float* __restrict__ colBv,
                                               const float* __restrict__ gRowA, const float* __restrict__ gRowC,
                                               const float* __restrict__ gColA, const float* __restrict__ gColC,
                                               float* __restrict__ O,
                                               float* __restrict__ sc_arrs,   // 8 arrays of 4096
                                               float* __restrict__ img_loss_arr,
                                               float* __restrict__ txt_loss_arr) {
    int j = blockIdx.x * 256 + threadIdx.x;
    if (j >= 2 * BDIM) return;
    bool rowside = (j < BDIM);
    int i = rowside ? j : j - BDIM;
    int id = ids[i];
    float tau  = rowside ? tau_I[id] : tau_T[id];
    float oldb = rowside ? b_I[id]   : b_T[id];
    float olds = rowside ? s_I[id]   : s_T[id];
    float oldu = rowside ? u_I[id]   : u_T[id];
    float nb   = rowside ? rowBv[i]  : colBv[i];
    float g    = rowside ? gRowA[i]  : gColA[i];
    float Cs   = rowside ? gRowC[i]  : gColC[i];
    float s_new = (1.f - C_GAMMA_S) * olds * __expf(oldb - nb) + C_GAMMA_S * g;
    float sc = fmaxf(s_new, C_EPS);
    float loss = Cs / sc;
    float grad = logf(sc) + nb + C_RHO - (Cs / (sc * tau)) * (1.0f / (float)(BDIM - 1));
    float gc = fminf(fmaxf(grad, -C_GRAD_CLIP), C_GRAD_CLIP);
    float u_new = (1.f - C_GAMMA_U) * oldu + C_GAMMA_U * gc;
    float tau_new = fminf(fmaxf(tau - C_ETA * u_new, C_TAU_MIN), C_TAU_MAX);
    if (rowside) {
        O[i] = g;
        O[8192 + i] = grad;
        sc_arrs[0 * BDIM + i] = s_new;
        sc_arrs[1 * BDIM + i] = nb;
        sc_arrs[2 * BDIM + i] = u_new;
        sc_arrs[3 * BDIM + i] = tau_new;
        img_loss_arr[i] = loss;
    } else {
        O[4096 + i] = g;
        O[12288 + i] = grad;
        sc_arrs[4 * BDIM + i] = s_new;
        sc_arrs[5 * BDIM + i] = nb;
        sc_arrs[6 * BDIM + i] = u_new;
        sc_arrs[7 * BDIM + i] = tau_new;
        txt_loss_arr[i] = loss;
    }
}

// ---------- K-scalars ----------
__global__ __launch_bounds__(256) void kscalars(const float* __restrict__ img_loss_arr,
                                                const float* __restrict__ txt_loss_arr,
                                                const int* __restrict__ ids,
                                                const float* __restrict__ tau_I,
                                                const float* __restrict__ tau_T,
                                                float* __restrict__ O) {
    int t = threadIdx.x;
    float s0 = 0.f, s1 = 0.f, s2 = 0.f, s3 = 0.f;
    for (int k = t; k < BDIM; k += 256) {
        s0 += img_loss_arr[k];
        s1 += txt_loss_arr[k];
        int id = ids[k];
        s2 += tau_I[id];
        s3 += tau_T[id];
    }
    __shared__ float r0[256], r1[256], r2[256], r3[256];
    r0[t] = s0; r1[t] = s1; r2[t] = s2; r3[t] = s3;
    __syncthreads();
    for (int s = 128; s > 0; s >>= 1) {
        if (t < s) {
            r0[t] += r0[t + s]; r1[t] += r1[t + s];
            r2[t] += r2[t + s]; r3[t] += r3[t + s];
        }
        __syncthreads();
    }
    if (t == 0) {
        float invB = 1.0f / (float)BDIM;
        O[16384] = C_ALPHA * (r0[0] * invB) + (1.f - C_ALPHA) * (r1[0] * invB);
        O[16385] = r2[0] * invB;
        O[16386] = r3[0] * invB;
    }
}

// ---------- K-scatter: patch updated rows into copied state ----------
__global__ __launch_bounds__(256) void kscatter(const int* __restrict__ ids,
                                                const float* __restrict__ sc_arrs,
                                                float* __restrict__ o) {
    int t = blockIdx.x * 256 + threadIdx.x;
    if (t >= BDIM) return;
    long id = ids[t];
    o[0L * NSTATE + id] = sc_arrs[0 * BDIM + t];
    o[1L * NSTATE + id] = sc_arrs[4 * BDIM + t];
    o[2L * NSTATE + id] = sc_arrs[1 * BDIM + t];
    o[3L * NSTATE + id] = sc_arrs[5 * BDIM + t];
    o[4L * NSTATE + id] = sc_arrs[2 * BDIM + t];
    o[5L * NSTATE + id] = sc_arrs[6 * BDIM + t];
    o[6L * NSTATE + id] = sc_arrs[3 * BDIM + t];
    o[7L * NSTATE + id] = sc_arrs[7 * BDIM + t];
}

extern "C" void kernel_launch(void* const* d_in, const int* in_sizes, int n_in,
                              void* d_out, int out_size, void* d_ws, size_t ws_size,
                              hipStream_t stream) {
    const float* zis   = (const float*)d_in[0];
    const float* zjs   = (const float*)d_in[1];
    const int*   ids   = (const int*)d_in[2];
    const float* s_I   = (const float*)d_in[3];
    const float* s_T   = (const float*)d_in[4];
    const float* b_I   = (const float*)d_in[5];
    const float* b_T   = (const float*)d_in[6];
    const float* u_I   = (const float*)d_in[7];
    const float* u_T   = (const float*)d_in[8];
    const float* tau_I = (const float*)d_in[9];
    const float* tau_T = (const float*)d_in[10];
    float* O  = (float*)d_out;
    float* ws = (float*)d_ws;

    // d_ws layout (float/u32 indices)
    unsigned* rowmaxE = (unsigned*)ws;            // 4096   (memset 0)
    unsigned* colmaxE = (unsigned*)(ws + 4096);   //        (memset 0)
    float* gRowA  = ws + 8192;                    //        (memset 0)
    float* gRowC  = ws + 12288;                   //        (memset 0)
    float* gColA  = ws + 16384;                   //        (memset 0)
    float* gColC  = ws + 20480;                   //        (memset 0)
    float* invnI  = ws + 24576;
    float* invnJ  = ws + 28672;
    float* diag   = ws + 32768;
    float* rowBv  = ws + 36864;
    float* rowIT  = ws + 40960;
    float* colBv  = ws + 45056;
    float* colIT  = ws + 49152;
    float* sc_arrs = ws + 53248;                  // 8 x 4096
    float* img_loss_arr = ws + 86016;
    float* txt_loss_arr = ws + 90112;

    hipMemsetAsync(d_ws, 0, 24576 * sizeof(float), stream);

    kinv<<<2 * BDIM, 256, 0, stream>>>(zis, zjs, invnI, invnJ);

    // pass A: maxima + diag, overlapped with copy of state banks 0-3
    kpass<0><<<1536, 256, 0, stream>>>(zis, zjs, invnI, invnJ,
                                       rowmaxE, colmaxE, diag,
                                       nullptr, nullptr, nullptr, nullptr,
                                       nullptr, nullptr, nullptr, nullptr,
                                       s_I, s_T, b_I, b_T, O + 16387);

    kmid<<<BDIM / 256, 256, 0, stream>>>(rowmaxE, colmaxE, diag, ids,
                                         b_I, tau_I, b_T, tau_T,
                                         rowBv, rowIT, colBv, colIT);

    // pass B: exp sums, overlapped with copy of state banks 4-7
    kpass<1><<<1536, 256, 0, stream>>>(zis, zjs, invnI, invnJ,
                                       rowmaxE, colmaxE, diag,
                                       rowBv, rowIT, colBv, colIT,
                                       gRowA, gRowC, gColA, gColC,
                                       u_I, u_T, tau_I, tau_T, O + 16387 + 4L * NSTATE);

    kfinal2<<<2 * BDIM / 256, 256, 0, stream>>>(ids, s_I, b_I, u_I, tau_I,
                                                s_T, b_T, u_T, tau_T,
                                                rowBv, colBv, gRowA, gRowC, gColA, gColC,
                                                O, sc_arrs, img_loss_arr, txt_loss_arr);

    kscalars<<<1, 256, 0, stream>>>(img_loss_arr, txt_loss_arr, ids, tau_I, tau_T, O);

    kscatter<<<BDIM / 256, 256, 0, stream>>>(ids, sc_arrs, O + 16387);
}

// Round 3
// 678.825 us; speedup vs baseline: 1.0617x; 1.0617x over previous
//
#include <hip/hip_runtime.h>
#include <math.h>

#define BDIM 4096
#define DDIM 256
#define NSTATE 9000000

#define C_ALPHA 0.5f
#define C_GAMMA_S 0.8f
#define C_GAMMA_U 0.9f
#define C_RHO 6.0f
#define C_EPS 1e-14f
#define C_ETA 0.01f
#define C_TAU_MIN 0.001f
#define C_TAU_MAX 1.0f
#define C_GRAD_CLIP 5.0f

// ---------- K0: inverse norms of zis (rows 0..B-1) and zjs (rows B..2B-1) ----------
__global__ __launch_bounds__(256) void kinv(const float* __restrict__ zis,
                                            const float* __restrict__ zjs,
                                            float* __restrict__ invnI,
                                            float* __restrict__ invnJ) {
    int row = blockIdx.x;
    int t = threadIdx.x;   // 256 == DDIM
    const float* src = (row < BDIM) ? zis + (size_t)row * DDIM
                                    : zjs + (size_t)(row - BDIM) * DDIM;
    float v = src[t];
    __shared__ float red[256];
    red[t] = v * v;
    __syncthreads();
    for (int s = 128; s > 0; s >>= 1) {
        if (t < s) red[t] += red[t + s];
        __syncthreads();
    }
    if (t == 0) {
        float inv = rsqrtf(red[0]);
        if (row < BDIM) invnI[row] = inv; else invnJ[row - BDIM] = inv;
    }
}

// ---------- K0b: 1/tau per row/col ----------
__global__ __launch_bounds__(256) void ktau(const int* __restrict__ ids,
                                            const float* __restrict__ tau_I,
                                            const float* __restrict__ tau_T,
                                            float* __restrict__ rowIT,
                                            float* __restrict__ colIT) {
    int i = blockIdx.x * 256 + threadIdx.x;
    if (i >= BDIM) return;
    int id = ids[i];
    rowIT[i] = 1.0f / tau_I[id];
    colIT[i] = 1.0f / tau_T[id];
}

// ---------- K1: single fused GEMM pass with online-LSE partial epilogue ----------
#define BMT 128
#define BNT 128
#define BKT 16

__device__ inline int rowIdxOf(int ty, int mi) { return ty * 4 + (mi & 3) + ((mi >> 2) << 6); }
__device__ inline int colIdxOf(int tx, int ni) { return tx * 4 + (ni & 3) + ((ni >> 2) << 6); }

__global__ __launch_bounds__(256) void kgemm(
    const float* __restrict__ ZA, const float* __restrict__ ZB,
    const float* __restrict__ invA, const float* __restrict__ invB,
    const float* __restrict__ rowIT, const float* __restrict__ colIT,
    float* __restrict__ rPM, float* __restrict__ rPS1, float* __restrict__ rPS2,
    float* __restrict__ cPM, float* __restrict__ cPS1, float* __restrict__ cPS2,
    float* __restrict__ diag)
{
    __shared__ float As[BKT][BMT + 4];
    __shared__ float Bs[BKT][BNT + 4];

    int bx = blockIdx.x, by = blockIdx.y;
    int t = threadIdx.x;
    int tx = t & 15, ty = t >> 4;
    int m0 = by * BMT, n0 = bx * BNT;
    int kq = (t & 3) * 4;   // 0,4,8,12
    int lrow = t >> 2;      // 0..63
    int w = t >> 6;         // wave 0..3

    float ivA0 = invA[m0 + lrow], ivA1 = invA[m0 + lrow + 64];
    float ivB0 = invB[n0 + lrow], ivB1 = invB[n0 + lrow + 64];

    float acc[8][8];
#pragma unroll
    for (int a = 0; a < 8; a++)
#pragma unroll
        for (int b = 0; b < 8; b++) acc[a][b] = 0.f;

    for (int k0 = 0; k0 < DDIM; k0 += BKT) {
        float4 a0 = *(const float4*)&ZA[(size_t)(m0 + lrow) * DDIM + k0 + kq];
        float4 a1 = *(const float4*)&ZA[(size_t)(m0 + lrow + 64) * DDIM + k0 + kq];
        float4 b0 = *(const float4*)&ZB[(size_t)(n0 + lrow) * DDIM + k0 + kq];
        float4 b1 = *(const float4*)&ZB[(size_t)(n0 + lrow + 64) * DDIM + k0 + kq];
        a0.x *= ivA0; a0.y *= ivA0; a0.z *= ivA0; a0.w *= ivA0;
        a1.x *= ivA1; a1.y *= ivA1; a1.z *= ivA1; a1.w *= ivA1;
        b0.x *= ivB0; b0.y *= ivB0; b0.z *= ivB0; b0.w *= ivB0;
        b1.x *= ivB1; b1.y *= ivB1; b1.z *= ivB1; b1.w *= ivB1;
        __syncthreads();
        As[kq + 0][lrow] = a0.x; As[kq + 1][lrow] = a0.y; As[kq + 2][lrow] = a0.z; As[kq + 3][lrow] = a0.w;
        As[kq + 0][lrow + 64] = a1.x; As[kq + 1][lrow + 64] = a1.y; As[kq + 2][lrow + 64] = a1.z; As[kq + 3][lrow + 64] = a1.w;
        Bs[kq + 0][lrow] = b0.x; Bs[kq + 1][lrow] = b0.y; Bs[kq + 2][lrow] = b0.z; Bs[kq + 3][lrow] = b0.w;
        Bs[kq + 0][lrow + 64] = b1.x; Bs[kq + 1][lrow + 64] = b1.y; Bs[kq + 2][lrow + 64] = b1.z; Bs[kq + 3][lrow + 64] = b1.w;
        __syncthreads();
#pragma unroll
        for (int k = 0; k < BKT; k++) {
            float4 t0 = *(const float4*)&As[k][ty * 4];
            float4 t1 = *(const float4*)&As[k][ty * 4 + 64];
            float4 t2 = *(const float4*)&Bs[k][tx * 4];
            float4 t3 = *(const float4*)&Bs[k][tx * 4 + 64];
            float am[8] = {t0.x, t0.y, t0.z, t0.w, t1.x, t1.y, t1.z, t1.w};
            float bn[8] = {t2.x, t2.y, t2.z, t2.w, t3.x, t3.y, t3.z, t3.w};
#pragma unroll
            for (int mi = 0; mi < 8; mi++)
#pragma unroll
                for (int ni = 0; ni < 8; ni++)
                    acc[mi][ni] = fmaf(am[mi], bn[ni], acc[mi][ni]);
        }
    }

    // ---- row partials: 16 tx-lanes per row (within one wave) ----
#pragma unroll
    for (int mi = 0; mi < 8; mi++) {
        int r = m0 + rowIdxOf(ty, mi);
        float it = rowIT[r];
        float m = acc[mi][0];
#pragma unroll
        for (int ni = 1; ni < 8; ni++) m = fmaxf(m, acc[mi][ni]);
#pragma unroll
        for (int off = 1; off < 16; off <<= 1) m = fmaxf(m, __shfl_xor(m, off));
        float s1 = 0.f, s2 = 0.f;
#pragma unroll
        for (int ni = 0; ni < 8; ni++) {
            float v = acc[mi][ni];
            float e = __expf((v - m) * it);
            s1 += e; s2 += e * v;
        }
#pragma unroll
        for (int off = 1; off < 16; off <<= 1) { s1 += __shfl_xor(s1, off); s2 += __shfl_xor(s2, off); }
        if (tx == 0) {
            rPM [bx * BDIM + r] = m;
            rPS1[bx * BDIM + r] = s1;
            rPS2[bx * BDIM + r] = s2;
        }
    }

    // ---- col partials: 4 ty-lanes per col within wave; one slot per (block-row, wave) ----
#pragma unroll
    for (int ni = 0; ni < 8; ni++) {
        int c = n0 + colIdxOf(tx, ni);
        float it = colIT[c];
        float m = acc[0][ni];
#pragma unroll
        for (int mi = 1; mi < 8; mi++) m = fmaxf(m, acc[mi][ni]);
        float s1 = 0.f, s2 = 0.f;
#pragma unroll
        for (int mi = 0; mi < 8; mi++) {
            float v = acc[mi][ni];
            float e = __expf((v - m) * it);
            s1 += e; s2 += e * v;
        }
#pragma unroll
        for (int off = 16; off < 64; off <<= 1) {
            float mo  = __shfl_xor(m, off);
            float s1o = __shfl_xor(s1, off);
            float s2o = __shfl_xor(s2, off);
            float M = fmaxf(m, mo);
            float ea = __expf((m - M) * it);
            float eb = __expf((mo - M) * it);
            s1 = s1 * ea + s1o * eb;
            s2 = s2 * ea + s2o * eb;
            m = M;
        }
        if ((t & 48) == 0) {   // first 16 lanes of each wave
            int slot = by * 4 + w;
            cPM [slot * BDIM + c] = m;
            cPS1[slot * BDIM + c] = s1;
            cPS2[slot * BDIM + c] = s2;
        }
    }

    // ---- diag ----
    if (bx == by && tx == ty) {
#pragma unroll
        for (int mi = 0; mi < 8; mi++) diag[m0 + rowIdxOf(ty, mi)] = acc[mi][mi];
    }
}

// ---------- K2: merge partials + full state math ----------
__global__ __launch_bounds__(256) void kmerge(
    const int* __restrict__ ids,
    const float* __restrict__ s_I, const float* __restrict__ b_I,
    const float* __restrict__ u_I, const float* __restrict__ tau_I,
    const float* __restrict__ s_T, const float* __restrict__ b_T,
    const float* __restrict__ u_T, const float* __restrict__ tau_T,
    const float* __restrict__ rowIT, const float* __restrict__ colIT,
    const float* __restrict__ diag,
    const float* __restrict__ rPM, const float* __restrict__ rPS1, const float* __restrict__ rPS2,
    const float* __restrict__ cPM, const float* __restrict__ cPS1, const float* __restrict__ cPS2,
    float* __restrict__ O,
    float* __restrict__ sc_arrs,
    float* __restrict__ img_loss_arr,
    float* __restrict__ txt_loss_arr)
{
    int j = blockIdx.x * 256 + threadIdx.x;
    if (j >= 2 * BDIM) return;
    bool rowside = (j < BDIM);
    int i = rowside ? j : j - BDIM;
    const float* PM  = rowside ? rPM  : cPM;
    const float* PS1 = rowside ? rPS1 : cPS1;
    const float* PS2 = rowside ? rPS2 : cPS2;
    int K = rowside ? 32 : 128;
    float it = rowside ? rowIT[i] : colIT[i];

    float M = -INFINITY, S1 = 0.f, S2 = 0.f;
    for (int k = 0; k < K; k++) {
        float m  = PM [k * BDIM + i];
        float s1 = PS1[k * BDIM + i];
        float s2 = PS2[k * BDIM + i];
        float Mn = fmaxf(M, m);
        float ea = __expf((M - Mn) * it);
        float eb = __expf((m - Mn) * it);
        S1 = S1 * ea + s1 * eb;
        S2 = S2 * ea + s2 * eb;
        M = Mn;
    }

    int id = ids[i];
    float tau  = rowside ? tau_I[id] : tau_T[id];
    float oldb = rowside ? b_I[id]   : b_T[id];
    float olds = rowside ? s_I[id]   : s_T[id];
    float oldu = rowside ? u_I[id]   : u_T[id];
    float dg = diag[i];

    float nb = fmaxf(oldb, (M - dg) * it);
    float F  = __expf((M - dg) * it - nb);
    float ed = __expf(-nb);                 // masked diagonal term
    float g  = F * S1 - ed;
    float Cs = F * (S2 - dg * S1);

    float s_new = (1.f - C_GAMMA_S) * olds * __expf(oldb - nb) + C_GAMMA_S * g;
    float sc = fmaxf(s_new, C_EPS);
    float loss = Cs / sc;
    float grad = logf(sc) + nb + C_RHO - (Cs / (sc * tau)) * (1.0f / (float)(BDIM - 1));
    float gc = fminf(fmaxf(grad, -C_GRAD_CLIP), C_GRAD_CLIP);
    float u_new = (1.f - C_GAMMA_U) * oldu + C_GAMMA_U * gc;
    float tau_new = fminf(fmaxf(tau - C_ETA * u_new, C_TAU_MIN), C_TAU_MAX);

    if (rowside) {
        O[i] = g;
        O[8192 + i] = grad;
        sc_arrs[0 * BDIM + i] = s_new;
        sc_arrs[1 * BDIM + i] = nb;
        sc_arrs[2 * BDIM + i] = u_new;
        sc_arrs[3 * BDIM + i] = tau_new;
        img_loss_arr[i] = loss;
    } else {
        O[4096 + i] = g;
        O[12288 + i] = grad;
        sc_arrs[4 * BDIM + i] = s_new;
        sc_arrs[5 * BDIM + i] = nb;
        sc_arrs[6 * BDIM + i] = u_new;
        sc_arrs[7 * BDIM + i] = tau_new;
        txt_loss_arr[i] = loss;
    }
}

// ---------- K3: scalar reductions ----------
__global__ __launch_bounds__(256) void kscalars(const float* __restrict__ img_loss_arr,
                                                const float* __restrict__ txt_loss_arr,
                                                const int* __restrict__ ids,
                                                const float* __restrict__ tau_I,
                                                const float* __restrict__ tau_T,
                                                float* __restrict__ O) {
    int t = threadIdx.x;
    float s0 = 0.f, s1 = 0.f, s2 = 0.f, s3 = 0.f;
    for (int k = t; k < BDIM; k += 256) {
        s0 += img_loss_arr[k];
        s1 += txt_loss_arr[k];
        int id = ids[k];
        s2 += tau_I[id];
        s3 += tau_T[id];
    }
    __shared__ float r0[256], r1[256], r2[256], r3[256];
    r0[t] = s0; r1[t] = s1; r2[t] = s2; r3[t] = s3;
    __syncthreads();
    for (int s = 128; s > 0; s >>= 1) {
        if (t < s) {
            r0[t] += r0[t + s]; r1[t] += r1[t + s];
            r2[t] += r2[t + s]; r3[t] += r3[t + s];
        }
        __syncthreads();
    }
    if (t == 0) {
        float invB = 1.0f / (float)BDIM;
        O[16384] = C_ALPHA * (r0[0] * invB) + (1.f - C_ALPHA) * (r1[0] * invB);
        O[16385] = r2[0] * invB;
        O[16386] = r3[0] * invB;
    }
}

// ---------- K4: bulk state copy (float4 loads, dword stores; dst 4B-aligned) ----------
__global__ __launch_bounds__(256) void kcopy(const float* __restrict__ s_I,
                                             const float* __restrict__ s_T,
                                             const float* __restrict__ b_I,
                                             const float* __restrict__ b_T,
                                             const float* __restrict__ u_I,
                                             const float* __restrict__ u_T,
                                             const float* __restrict__ tau_I,
                                             const float* __restrict__ tau_T,
                                             float* __restrict__ o) {
    const float4* srcs[8] = {(const float4*)s_I, (const float4*)s_T,
                             (const float4*)b_I, (const float4*)b_T,
                             (const float4*)u_I, (const float4*)u_T,
                             (const float4*)tau_I, (const float4*)tau_T};
    long tid = (long)blockIdx.x * 256 + threadIdx.x;   // grid 8192 -> 2,097,152 threads
#pragma unroll
    for (int b = 0; b < 8; b++) {
        const float4* s = srcs[b];
        float* d = o + (long)b * NSTATE;
        for (long k = tid; k < NSTATE / 4; k += 2097152) {
            float4 v = s[k];
            float* dp = d + 4 * k;
            dp[0] = v.x; dp[1] = v.y; dp[2] = v.z; dp[3] = v.w;
        }
    }
}

// ---------- K5: scatter updated state at ids ----------
__global__ __launch_bounds__(256) void kscatter(const int* __restrict__ ids,
                                                const float* __restrict__ sc_arrs,
                                                float* __restrict__ o) {
    int t = blockIdx.x * 256 + threadIdx.x;
    if (t >= BDIM) return;
    long id = ids[t];
    o[0L * NSTATE + id] = sc_arrs[0 * BDIM + t];
    o[1L * NSTATE + id] = sc_arrs[4 * BDIM + t];
    o[2L * NSTATE + id] = sc_arrs[1 * BDIM + t];
    o[3L * NSTATE + id] = sc_arrs[5 * BDIM + t];
    o[4L * NSTATE + id] = sc_arrs[2 * BDIM + t];
    o[5L * NSTATE + id] = sc_arrs[6 * BDIM + t];
    o[6L * NSTATE + id] = sc_arrs[3 * BDIM + t];
    o[7L * NSTATE + id] = sc_arrs[7 * BDIM + t];
}

extern "C" void kernel_launch(void* const* d_in, const int* in_sizes, int n_in,
                              void* d_out, int out_size, void* d_ws, size_t ws_size,
                              hipStream_t stream) {
    const float* zis   = (const float*)d_in[0];
    const float* zjs   = (const float*)d_in[1];
    const int*   ids   = (const int*)d_in[2];
    const float* s_I   = (const float*)d_in[3];
    const float* s_T   = (const float*)d_in[4];
    const float* b_I   = (const float*)d_in[5];
    const float* b_T   = (const float*)d_in[6];
    const float* u_I   = (const float*)d_in[7];
    const float* u_T   = (const float*)d_in[8];
    const float* tau_I = (const float*)d_in[9];
    const float* tau_T = (const float*)d_in[10];
    float* O  = (float*)d_out;
    float* ws = (float*)d_ws;

    // big partials live in d_out's state region (consumed by kmerge, then
    // overwritten by kcopy). Base at 16388 -> 16B aligned.
    float* pBase = O + 16388;
    float* rPM  = pBase;                 // 32 * 4096
    float* rPS1 = pBase + 131072;
    float* rPS2 = pBase + 262144;
    float* cPM  = pBase + 393216;        // 128 * 4096
    float* cPS1 = pBase + 917504;
    float* cPS2 = pBase + 1441792;

    // small arrays in ws
    float* invnI  = ws;                  // 4096 each
    float* invnJ  = ws + 4096;
    float* rowIT  = ws + 8192;
    float* colIT  = ws + 12288;
    float* diag   = ws + 16384;
    float* sc_arrs = ws + 20480;         // 8 x 4096
    float* img_loss_arr = ws + 53248;
    float* txt_loss_arr = ws + 57344;

    kinv<<<2 * BDIM, 256, 0, stream>>>(zis, zjs, invnI, invnJ);
    ktau<<<16, 256, 0, stream>>>(ids, tau_I, tau_T, rowIT, colIT);

    kgemm<<<dim3(32, 32), 256, 0, stream>>>(zis, zjs, invnI, invnJ, rowIT, colIT,
                                            rPM, rPS1, rPS2, cPM, cPS1, cPS2, diag);

    kmerge<<<32, 256, 0, stream>>>(ids, s_I, b_I, u_I, tau_I, s_T, b_T, u_T, tau_T,
                                   rowIT, colIT, diag,
                                   rPM, rPS1, rPS2, cPM, cPS1, cPS2,
                                   O, sc_arrs, img_loss_arr, txt_loss_arr);

    kscalars<<<1, 256, 0, stream>>>(img_loss_arr, txt_loss_arr, ids, tau_I, tau_T, O);

    kcopy<<<8192, 256, 0, stream>>>(s_I, s_T, b_I, b_T, u_I, u_T, tau_I, tau_T, O + 16387);

    kscatter<<<16, 256, 0, stream>>>(ids, sc_arrs, O + 16387);
}

// Round 4
// 556.963 us; speedup vs baseline: 1.2940x; 1.2188x over previous
//
#include <hip/hip_runtime.h>
#include <math.h>

#define BDIM 4096
#define DDIM 256
#define NSTATE 9000000

#define C_ALPHA 0.5f
#define C_GAMMA_S 0.8f
#define C_GAMMA_U 0.9f
#define C_RHO 6.0f
#define C_EPS 1e-14f
#define C_ETA 0.01f
#define C_TAU_MIN 0.001f
#define C_TAU_MAX 1.0f
#define C_GRAD_CLIP 5.0f

typedef unsigned short u16;
typedef __attribute__((ext_vector_type(8))) short short8;
typedef __attribute__((ext_vector_type(16))) float f32x16;

#define MFMA32 __builtin_amdgcn_mfma_f32_32x32x16_bf16

__device__ inline u16 f2bf(float f) {
    unsigned u = __float_as_uint(f);
    unsigned r = (u + 0x7FFFu + ((u >> 16) & 1u)) >> 16;
    return (u16)r;
}
__device__ inline float bf2f(u16 h) { return __uint_as_float(((unsigned)h) << 16); }

// ---------- K0: 1/tau per row/col ----------
__global__ __launch_bounds__(256) void ktau(const int* __restrict__ ids,
                                            const float* __restrict__ tau_I,
                                            const float* __restrict__ tau_T,
                                            float* __restrict__ rowIT,
                                            float* __restrict__ colIT) {
    int i = blockIdx.x * 256 + threadIdx.x;
    if (i >= BDIM) return;
    int id = ids[i];
    rowIT[i] = 1.0f / tau_I[id];
    colIT[i] = 1.0f / tau_T[id];
}

// ---------- K1: normalize + split to bf16 hi/lo in MFMA-fragment-swizzled layout ----------
// swizzle: elem(row,k) -> ((row>>5)*1024 + (k>>3)*32 + (row&31))*8 + (k&7)
// so a 32x32x16 A/B fragment (lane l, kstep s) is 16 contiguous bytes at
// base = R*8192 + s*512 elements, lane offset l*8.
__global__ __launch_bounds__(256) void kprep(const float* __restrict__ zis,
                                             const float* __restrict__ zjs,
                                             u16* __restrict__ Ah, u16* __restrict__ Al,
                                             u16* __restrict__ Bh, u16* __restrict__ Bl) {
    int blk = blockIdx.x;                 // 0..255
    bool isB = blk >= 128;
    const float* Z = isB ? zjs : zis;
    u16* H = isB ? Bh : Ah;
    u16* L = isB ? Bl : Al;
    int rblk = blk & 127;
    int t = threadIdx.x;
    int r = t & 31, kc0 = t >> 5;         // 8 threads per row
    int row = rblk * 32 + r;

    __shared__ float ssq[32];
    if (t < 32) ssq[t] = 0.f;
    __syncthreads();

    float4 v[8];
    float partial = 0.f;
#pragma unroll
    for (int c = 0; c < 4; ++c) {
        int kc = kc0 + 8 * c;
        float4 a = *(const float4*)&Z[(size_t)row * DDIM + kc * 8];
        float4 b = *(const float4*)&Z[(size_t)row * DDIM + kc * 8 + 4];
        v[2 * c] = a; v[2 * c + 1] = b;
        partial += a.x * a.x + a.y * a.y + a.z * a.z + a.w * a.w;
        partial += b.x * b.x + b.y * b.y + b.z * b.z + b.w * b.w;
    }
    atomicAdd(&ssq[r], partial);
    __syncthreads();
    float inv = rsqrtf(ssq[r]);

#pragma unroll
    for (int c = 0; c < 4; ++c) {
        int kc = kc0 + 8 * c;
        float f[8];
        f[0] = v[2*c].x * inv;   f[1] = v[2*c].y * inv;
        f[2] = v[2*c].z * inv;   f[3] = v[2*c].w * inv;
        f[4] = v[2*c+1].x * inv; f[5] = v[2*c+1].y * inv;
        f[6] = v[2*c+1].z * inv; f[7] = v[2*c+1].w * inv;
        u16 hh[8], ll[8];
#pragma unroll
        for (int j = 0; j < 8; ++j) {
            hh[j] = f2bf(f[j]);
            ll[j] = f2bf(f[j] - bf2f(hh[j]));
        }
        size_t base = (size_t)rblk * 8192 + (size_t)kc * 256 + (size_t)r * 8;
        uint4 ph, pl;
        ph.x = (unsigned)hh[0] | ((unsigned)hh[1] << 16);
        ph.y = (unsigned)hh[2] | ((unsigned)hh[3] << 16);
        ph.z = (unsigned)hh[4] | ((unsigned)hh[5] << 16);
        ph.w = (unsigned)hh[6] | ((unsigned)hh[7] << 16);
        pl.x = (unsigned)ll[0] | ((unsigned)ll[1] << 16);
        pl.y = (unsigned)ll[2] | ((unsigned)ll[3] << 16);
        pl.z = (unsigned)ll[4] | ((unsigned)ll[5] << 16);
        pl.w = (unsigned)ll[6] | ((unsigned)ll[7] << 16);
        *(uint4*)(H + base) = ph;
        *(uint4*)(L + base) = pl;
    }
}

// ---------- K2: MFMA GEMM, fragments direct from global, no K-loop barriers ----------
// block 128x128, 4 waves in 2x2; wave tile 64x64 (2x2 of 32x32).
__global__ __launch_bounds__(256, 3) void kgemm(
    const u16* __restrict__ Ah, const u16* __restrict__ Al,
    const u16* __restrict__ Bh, const u16* __restrict__ Bl,
    const float* __restrict__ rowIT, const float* __restrict__ colIT,
    float* __restrict__ rPM, float* __restrict__ rPS1, float* __restrict__ rPS2,
    float* __restrict__ cPM, float* __restrict__ cPS1, float* __restrict__ cPS2,
    float* __restrict__ diag)
{
    __shared__ float T[2][64 * 68];

    int bx = blockIdx.x, by = blockIdx.y;
    int t = threadIdx.x;
    int w = t >> 6, l = t & 63;
    int rw = w & 1, cw = w >> 1;
    int h = l >> 5, lc = l & 31;
    int rowbase = by * 128 + rw * 64;
    int colbase = bx * 128 + cw * 64;

    const u16* pAh = Ah + (size_t)(by * 4 + rw * 2) * 8192;
    const u16* pAl = Al + (size_t)(by * 4 + rw * 2) * 8192;
    const u16* pBh = Bh + (size_t)(bx * 4 + cw * 2) * 8192;
    const u16* pBl = Bl + (size_t)(bx * 4 + cw * 2) * 8192;

    f32x16 acc00, acc01, acc10, acc11;
#pragma unroll
    for (int e = 0; e < 16; ++e) { acc00[e] = 0.f; acc01[e] = 0.f; acc10[e] = 0.f; acc11[e] = 0.f; }

    for (int s = 0; s < 16; ++s) {
        int off = s * 512 + l * 8;
        short8 a0h = *(const short8*)(pAh + off);
        short8 a1h = *(const short8*)(pAh + 8192 + off);
        short8 a0l = *(const short8*)(pAl + off);
        short8 a1l = *(const short8*)(pAl + 8192 + off);
        short8 b0h = *(const short8*)(pBh + off);
        short8 b1h = *(const short8*)(pBh + 8192 + off);
        short8 b0l = *(const short8*)(pBl + off);
        short8 b1l = *(const short8*)(pBl + 8192 + off);

        acc00 = MFMA32(a0h, b0h, acc00, 0, 0, 0);
        acc01 = MFMA32(a0h, b1h, acc01, 0, 0, 0);
        acc10 = MFMA32(a1h, b0h, acc10, 0, 0, 0);
        acc11 = MFMA32(a1h, b1h, acc11, 0, 0, 0);
        acc00 = MFMA32(a0h, b0l, acc00, 0, 0, 0);
        acc01 = MFMA32(a0h, b1l, acc01, 0, 0, 0);
        acc10 = MFMA32(a1h, b0l, acc10, 0, 0, 0);
        acc11 = MFMA32(a1h, b1l, acc11, 0, 0, 0);
        acc00 = MFMA32(a0l, b0h, acc00, 0, 0, 0);
        acc01 = MFMA32(a0l, b1h, acc01, 0, 0, 0);
        acc10 = MFMA32(a1l, b0h, acc10, 0, 0, 0);
        acc11 = MFMA32(a1l, b1h, acc11, 0, 0, 0);
    }

    // ---- col partials (register path): C/D col = lane&31 ----
#define COLPART(A0, A1, CT) do {                                                   \
        int gc = colbase + (CT) * 32 + lc;                                         \
        float itc = colIT[gc];                                                     \
        float m = -INFINITY;                                                       \
        _Pragma("unroll") for (int e = 0; e < 16; ++e) {                           \
            m = fmaxf(m, (A0)[e]); m = fmaxf(m, (A1)[e]); }                        \
        m = fmaxf(m, __shfl_xor(m, 32));                                           \
        float S1 = 0.f, S2 = 0.f;                                                  \
        _Pragma("unroll") for (int e = 0; e < 16; ++e) {                           \
            float v0 = (A0)[e]; float e0 = __expf((v0 - m) * itc); S1 += e0; S2 += e0 * v0; \
            float v1 = (A1)[e]; float e1 = __expf((v1 - m) * itc); S1 += e1; S2 += e1 * v1; } \
        S1 += __shfl_xor(S1, 32); S2 += __shfl_xor(S2, 32);                        \
        if (h == 0) { int slot = by * 2 + rw;                                      \
            cPM [slot * 4096 + gc] = m;                                            \
            cPS1[slot * 4096 + gc] = S1;                                           \
            cPS2[slot * 4096 + gc] = S2; }                                         \
    } while (0)

    COLPART(acc00, acc10, 0);
    COLPART(acc01, acc11, 1);

    // ---- row partials via per-wave LDS transpose ----
    // dump layout T[r][c], stride 68; C/D row = (reg&3) + 8*(reg>>2) + 4*h
#define ROWPART(TB) do {                                                           \
        float* Tb = (TB);                                                          \
        _Pragma("unroll") for (int q = 0; q < 4; ++q) {                            \
            _Pragma("unroll") for (int j = 0; j < 4; ++j) {                        \
                int rr = 8 * q + 4 * h + j;                                        \
                Tb[(rr     ) * 68 + lc     ] = acc00[4 * q + j];                   \
                Tb[(rr     ) * 68 + lc + 32] = acc01[4 * q + j];                   \
                Tb[(rr + 32) * 68 + lc     ] = acc10[4 * q + j];                   \
                Tb[(rr + 32) * 68 + lc + 32] = acc11[4 * q + j]; } }               \
        float itr = rowIT[rowbase + l];                                            \
        float4 vv[16];                                                             \
        _Pragma("unroll") for (int c = 0; c < 16; ++c)                             \
            vv[c] = *(const float4*)&Tb[l * 68 + 4 * c];                           \
        float m = -INFINITY;                                                       \
        _Pragma("unroll") for (int c = 0; c < 16; ++c)                             \
            m = fmaxf(m, fmaxf(fmaxf(vv[c].x, vv[c].y), fmaxf(vv[c].z, vv[c].w))); \
        float S1 = 0.f, S2 = 0.f;                                                  \
        _Pragma("unroll") for (int c = 0; c < 16; ++c) {                           \
            float e0 = __expf((vv[c].x - m) * itr); S1 += e0; S2 += e0 * vv[c].x;  \
            float e1 = __expf((vv[c].y - m) * itr); S1 += e1; S2 += e1 * vv[c].y;  \
            float e2 = __expf((vv[c].z - m) * itr); S1 += e2; S2 += e2 * vv[c].z;  \
            float e3 = __expf((vv[c].w - m) * itr); S1 += e3; S2 += e3 * vv[c].w; }\
        int slot = bx * 2 + cw;                                                    \
        rPM [slot * 4096 + rowbase + l] = m;                                       \
        rPS1[slot * 4096 + rowbase + l] = S1;                                      \
        rPS2[slot * 4096 + rowbase + l] = S2;                                      \
        if (bx == by && rw == cw) diag[rowbase + l] = Tb[l * 68 + l];              \
    } while (0)

    if (w < 2) ROWPART(T[w]);
    __syncthreads();
    if (w >= 2) ROWPART(T[w - 2]);
}

// ---------- K3: merge partials + full state math ----------
__global__ __launch_bounds__(256) void kmerge(
    const int* __restrict__ ids,
    const float* __restrict__ s_I, const float* __restrict__ b_I,
    const float* __restrict__ u_I, const float* __restrict__ tau_I,
    const float* __restrict__ s_T, const float* __restrict__ b_T,
    const float* __restrict__ u_T, const float* __restrict__ tau_T,
    const float* __restrict__ rowIT, const float* __restrict__ colIT,
    const float* __restrict__ diag,
    const float* __restrict__ rPM, const float* __restrict__ rPS1, const float* __restrict__ rPS2,
    const float* __restrict__ cPM, const float* __restrict__ cPS1, const float* __restrict__ cPS2,
    float* __restrict__ O,
    float* __restrict__ sc_arrs,
    float* __restrict__ img_loss_arr,
    float* __restrict__ txt_loss_arr)
{
    int j = blockIdx.x * 256 + threadIdx.x;
    if (j >= 2 * BDIM) return;
    bool rowside = (j < BDIM);
    int i = rowside ? j : j - BDIM;
    const float* PM  = rowside ? rPM  : cPM;
    const float* PS1 = rowside ? rPS1 : cPS1;
    const float* PS2 = rowside ? rPS2 : cPS2;
    float it = rowside ? rowIT[i] : colIT[i];

    float M = -INFINITY, S1 = 0.f, S2 = 0.f;
    for (int k = 0; k < 64; k++) {
        float m  = PM [k * BDIM + i];
        float s1 = PS1[k * BDIM + i];
        float s2 = PS2[k * BDIM + i];
        float Mn = fmaxf(M, m);
        float ea = __expf((M - Mn) * it);
        float eb = __expf((m - Mn) * it);
        S1 = S1 * ea + s1 * eb;
        S2 = S2 * ea + s2 * eb;
        M = Mn;
    }

    int id = ids[i];
    float tau  = rowside ? tau_I[id] : tau_T[id];
    float oldb = rowside ? b_I[id]   : b_T[id];
    float olds = rowside ? s_I[id]   : s_T[id];
    float oldu = rowside ? u_I[id]   : u_T[id];
    float dg = diag[i];

    float nb = fmaxf(oldb, (M - dg) * it);
    float F  = __expf((M - dg) * it - nb);
    float ed = __expf(-nb);                 // masked diagonal term
    float g  = F * S1 - ed;
    float Cs = F * (S2 - dg * S1);

    float s_new = (1.f - C_GAMMA_S) * olds * __expf(oldb - nb) + C_GAMMA_S * g;
    float sc = fmaxf(s_new, C_EPS);
    float loss = Cs / sc;
    float grad = logf(sc) + nb + C_RHO - (Cs / (sc * tau)) * (1.0f / (float)(BDIM - 1));
    float gc = fminf(fmaxf(grad, -C_GRAD_CLIP), C_GRAD_CLIP);
    float u_new = (1.f - C_GAMMA_U) * oldu + C_GAMMA_U * gc;
    float tau_new = fminf(fmaxf(tau - C_ETA * u_new, C_TAU_MIN), C_TAU_MAX);

    if (rowside) {
        O[i] = g;
        O[8192 + i] = grad;
        sc_arrs[0 * BDIM + i] = s_new;
        sc_arrs[1 * BDIM + i] = nb;
        sc_arrs[2 * BDIM + i] = u_new;
        sc_arrs[3 * BDIM + i] = tau_new;
        img_loss_arr[i] = loss;
    } else {
        O[4096 + i] = g;
        O[12288 + i] = grad;
        sc_arrs[4 * BDIM + i] = s_new;
        sc_arrs[5 * BDIM + i] = nb;
        sc_arrs[6 * BDIM + i] = u_new;
        sc_arrs[7 * BDIM + i] = tau_new;
        txt_loss_arr[i] = loss;
    }
}

// ---------- K4: scalar reductions ----------
__global__ __launch_bounds__(256) void kscalars(const float* __restrict__ img_loss_arr,
                                                const float* __restrict__ txt_loss_arr,
                                                const int* __restrict__ ids,
                                                const float* __restrict__ tau_I,
                                                const float* __restrict__ tau_T,
                                                float* __restrict__ O) {
    int t = threadIdx.x;
    float s0 = 0.f, s1 = 0.f, s2 = 0.f, s3 = 0.f;
    for (int k = t; k < BDIM; k += 256) {
        s0 += img_loss_arr[k];
        s1 += txt_loss_arr[k];
        int id = ids[k];
        s2 += tau_I[id];
        s3 += tau_T[id];
    }
    __shared__ float r0[256], r1[256], r2[256], r3[256];
    r0[t] = s0; r1[t] = s1; r2[t] = s2; r3[t] = s3;
    __syncthreads();
    for (int s = 128; s > 0; s >>= 1) {
        if (t < s) {
            r0[t] += r0[t + s]; r1[t] += r1[t + s];
            r2[t] += r2[t + s]; r3[t] += r3[t + s];
        }
        __syncthreads();
    }
    if (t == 0) {
        float invB = 1.0f / (float)BDIM;
        O[16384] = C_ALPHA * (r0[0] * invB) + (1.f - C_ALPHA) * (r1[0] * invB);
        O[16385] = r2[0] * invB;
        O[16386] = r3[0] * invB;
    }
}

// ---------- K5: bulk state copy ----------
__global__ __launch_bounds__(256) void kcopy(const float* __restrict__ s_I,
                                             const float* __restrict__ s_T,
                                             const float* __restrict__ b_I,
                                             const float* __restrict__ b_T,
                                             const float* __restrict__ u_I,
                                             const float* __restrict__ u_T,
                                             const float* __restrict__ tau_I,
                                             const float* __restrict__ tau_T,
                                             float* __restrict__ o) {
    const float4* srcs[8] = {(const float4*)s_I, (const float4*)s_T,
                             (const float4*)b_I, (const float4*)b_T,
                             (const float4*)u_I, (const float4*)u_T,
                             (const float4*)tau_I, (const float4*)tau_T};
    long tid = (long)blockIdx.x * 256 + threadIdx.x;   // grid 8192 -> 2,097,152 threads
#pragma unroll
    for (int b = 0; b < 8; b++) {
        const float4* s = srcs[b];
        float* d = o + (long)b * NSTATE;
        for (long k = tid; k < NSTATE / 4; k += 2097152) {
            float4 v = s[k];
            float* dp = d + 4 * k;
            dp[0] = v.x; dp[1] = v.y; dp[2] = v.z; dp[3] = v.w;
        }
    }
}

// ---------- K6: scatter updated state at ids ----------
__global__ __launch_bounds__(256) void kscatter(const int* __restrict__ ids,
                                                const float* __restrict__ sc_arrs,
                                                float* __restrict__ o) {
    int t = blockIdx.x * 256 + threadIdx.x;
    if (t >= BDIM) return;
    long id = ids[t];
    o[0L * NSTATE + id] = sc_arrs[0 * BDIM + t];
    o[1L * NSTATE + id] = sc_arrs[4 * BDIM + t];
    o[2L * NSTATE + id] = sc_arrs[1 * BDIM + t];
    o[3L * NSTATE + id] = sc_arrs[5 * BDIM + t];
    o[4L * NSTATE + id] = sc_arrs[2 * BDIM + t];
    o[5L * NSTATE + id] = sc_arrs[6 * BDIM + t];
    o[6L * NSTATE + id] = sc_arrs[3 * BDIM + t];
    o[7L * NSTATE + id] = sc_arrs[7 * BDIM + t];
}

extern "C" void kernel_launch(void* const* d_in, const int* in_sizes, int n_in,
                              void* d_out, int out_size, void* d_ws, size_t ws_size,
                              hipStream_t stream) {
    const float* zis   = (const float*)d_in[0];
    const float* zjs   = (const float*)d_in[1];
    const int*   ids   = (const int*)d_in[2];
    const float* s_I   = (const float*)d_in[3];
    const float* s_T   = (const float*)d_in[4];
    const float* b_I   = (const float*)d_in[5];
    const float* b_T   = (const float*)d_in[6];
    const float* u_I   = (const float*)d_in[7];
    const float* u_T   = (const float*)d_in[8];
    const float* tau_I = (const float*)d_in[9];
    const float* tau_T = (const float*)d_in[10];
    float* O  = (float*)d_out;
    float* ws = (float*)d_ws;

    // scratch in d_out's state region (consumed before kcopy overwrites it)
    float* P = O + 16388;                       // 16B-aligned
    float* rPM  = P;                            // 64*4096 each
    float* rPS1 = P + 262144;
    float* rPS2 = P + 524288;
    float* cPM  = P + 786432;
    float* cPS1 = P + 1048576;
    float* cPS2 = P + 1310720;
    float* diag = P + 1572864;                  // 4096
    u16* AB = (u16*)(P + 1576960);              // 4 x 1,048,576 bf16
    u16* Ah = AB;
    u16* Al = AB + 1048576;
    u16* Bh = AB + 2097152;
    u16* Bl = AB + 3145728;

    // small arrays in ws
    float* rowIT  = ws;                         // 4096 each
    float* colIT  = ws + 4096;
    float* sc_arrs = ws + 8192;                 // 8 x 4096
    float* img_loss_arr = ws + 40960;
    float* txt_loss_arr = ws + 45056;

    ktau<<<16, 256, 0, stream>>>(ids, tau_I, tau_T, rowIT, colIT);
    kprep<<<256, 256, 0, stream>>>(zis, zjs, Ah, Al, Bh, Bl);

    kgemm<<<dim3(32, 32), 256, 0, stream>>>(Ah, Al, Bh, Bl, rowIT, colIT,
                                            rPM, rPS1, rPS2, cPM, cPS1, cPS2, diag);

    kmerge<<<32, 256, 0, stream>>>(ids, s_I, b_I, u_I, tau_I, s_T, b_T, u_T, tau_T,
                                   rowIT, colIT, diag,
                                   rPM, rPS1, rPS2, cPM, cPS1, cPS2,
                                   O, sc_arrs, img_loss_arr, txt_loss_arr);

    kscalars<<<1, 256, 0, stream>>>(img_loss_arr, txt_loss_arr, ids, tau_I, tau_T, O);

    kcopy<<<8192, 256, 0, stream>>>(s_I, s_T, b_I, b_T, u_I, u_T, tau_I, tau_T, O + 16387);

    kscatter<<<16, 256, 0, stream>>>(ids, sc_arrs, O + 16387);
}

// Round 5
// 552.411 us; speedup vs baseline: 1.3046x; 1.0082x over previous
//
#include <hip/hip_runtime.h>
#include <math.h>

#define BDIM 4096
#define DDIM 256
#define NSTATE 9000000
// bank-0 prefix holding live scratch (partials + bf16 fragments), copied late:
#define PREFIX 3674116
#define BANK0_N4 1331471     // (NSTATE - PREFIX) / 4
#define PREFIX_N4 918529     // PREFIX / 4
#define COPY_THREADS 1048576 // 4096 copy blocks * 256

#define C_ALPHA 0.5f
#define C_GAMMA_S 0.8f
#define C_GAMMA_U 0.9f
#define C_RHO 6.0f
#define C_EPS 1e-14f
#define C_ETA 0.01f
#define C_TAU_MIN 0.001f
#define C_TAU_MAX 1.0f
#define C_GRAD_CLIP 5.0f

typedef unsigned short u16;
typedef __attribute__((ext_vector_type(8))) short short8;
typedef __attribute__((ext_vector_type(16))) float f32x16;
typedef __attribute__((ext_vector_type(4))) float nf4;

#define MFMA32 __builtin_amdgcn_mfma_f32_32x32x16_bf16

__device__ inline u16 f2bf(float f) {
    unsigned u = __float_as_uint(f);
    unsigned r = (u + 0x7FFFu + ((u >> 16) & 1u)) >> 16;
    return (u16)r;
}
__device__ inline float bf2f(u16 h) { return __uint_as_float(((unsigned)h) << 16); }

__device__ inline void nt_copy4(const nf4* __restrict__ s, long k, float* __restrict__ dbase) {
    nf4 v = __builtin_nontemporal_load(&s[k]);
    float* dp = dbase + 4 * k;
    __builtin_nontemporal_store(v.x, dp + 0);
    __builtin_nontemporal_store(v.y, dp + 1);
    __builtin_nontemporal_store(v.z, dp + 2);
    __builtin_nontemporal_store(v.w, dp + 3);
}

// ---------- K1: normalize + split to bf16 hi/lo in MFMA-fragment layout; block 256 does 1/tau ----------
__global__ __launch_bounds__(256) void kprep(const float* __restrict__ zis,
                                             const float* __restrict__ zjs,
                                             u16* __restrict__ Ah, u16* __restrict__ Al,
                                             u16* __restrict__ Bh, u16* __restrict__ Bl,
                                             const int* __restrict__ ids,
                                             const float* __restrict__ tau_I,
                                             const float* __restrict__ tau_T,
                                             float* __restrict__ rowIT,
                                             float* __restrict__ colIT) {
    int blk = blockIdx.x;                 // 0..256
    int t = threadIdx.x;
    if (blk == 256) {
        for (int i = t; i < BDIM; i += 256) {
            int id = ids[i];
            rowIT[i] = 1.0f / tau_I[id];
            colIT[i] = 1.0f / tau_T[id];
        }
        return;
    }
    bool isB = blk >= 128;
    const float* Z = isB ? zjs : zis;
    u16* H = isB ? Bh : Ah;
    u16* L = isB ? Bl : Al;
    int rblk = blk & 127;
    int r = t & 31, kc0 = t >> 5;         // 8 threads per row
    int row = rblk * 32 + r;

    __shared__ float ssq[32];
    if (t < 32) ssq[t] = 0.f;
    __syncthreads();

    float4 v[8];
    float partial = 0.f;
#pragma unroll
    for (int c = 0; c < 4; ++c) {
        int kc = kc0 + 8 * c;
        float4 a = *(const float4*)&Z[(size_t)row * DDIM + kc * 8];
        float4 b = *(const float4*)&Z[(size_t)row * DDIM + kc * 8 + 4];
        v[2 * c] = a; v[2 * c + 1] = b;
        partial += a.x * a.x + a.y * a.y + a.z * a.z + a.w * a.w;
        partial += b.x * b.x + b.y * b.y + b.z * b.z + b.w * b.w;
    }
    atomicAdd(&ssq[r], partial);
    __syncthreads();
    float inv = rsqrtf(ssq[r]);

#pragma unroll
    for (int c = 0; c < 4; ++c) {
        int kc = kc0 + 8 * c;
        float f[8];
        f[0] = v[2*c].x * inv;   f[1] = v[2*c].y * inv;
        f[2] = v[2*c].z * inv;   f[3] = v[2*c].w * inv;
        f[4] = v[2*c+1].x * inv; f[5] = v[2*c+1].y * inv;
        f[6] = v[2*c+1].z * inv; f[7] = v[2*c+1].w * inv;
        u16 hh[8], ll[8];
#pragma unroll
        for (int j = 0; j < 8; ++j) {
            hh[j] = f2bf(f[j]);
            ll[j] = f2bf(f[j] - bf2f(hh[j]));
        }
        size_t base = (size_t)rblk * 8192 + (size_t)kc * 256 + (size_t)r * 8;
        uint4 ph, pl;
        ph.x = (unsigned)hh[0] | ((unsigned)hh[1] << 16);
        ph.y = (unsigned)hh[2] | ((unsigned)hh[3] << 16);
        ph.z = (unsigned)hh[4] | ((unsigned)hh[5] << 16);
        ph.w = (unsigned)hh[6] | ((unsigned)hh[7] << 16);
        pl.x = (unsigned)ll[0] | ((unsigned)ll[1] << 16);
        pl.y = (unsigned)ll[2] | ((unsigned)ll[3] << 16);
        pl.z = (unsigned)ll[4] | ((unsigned)ll[5] << 16);
        pl.w = (unsigned)ll[6] | ((unsigned)ll[7] << 16);
        *(uint4*)(H + base) = ph;
        *(uint4*)(L + base) = pl;
    }
}

// ---------- K2: fused MFMA GEMM (1024 blocks) + nontemporal state copy (4096 blocks) ----------
__global__ __launch_bounds__(256, 3) void kmain(
    const u16* __restrict__ Ah, const u16* __restrict__ Al,
    const u16* __restrict__ Bh, const u16* __restrict__ Bl,
    const float* __restrict__ rowIT, const float* __restrict__ colIT,
    float* __restrict__ rPM, float* __restrict__ rPS1, float* __restrict__ rPS2,
    float* __restrict__ cPM, float* __restrict__ cPS1, float* __restrict__ cPS2,
    float* __restrict__ diag,
    const float* __restrict__ s_I, const float* __restrict__ s_T,
    const float* __restrict__ b_I, const float* __restrict__ b_T,
    const float* __restrict__ u_I, const float* __restrict__ u_T,
    const float* __restrict__ tau_I, const float* __restrict__ tau_T,
    float* o)
{
    __shared__ float T[2][64 * 68];
    int bid = blockIdx.x;
    int t = threadIdx.x;

    if (bid % 5 != 0) {
        // ---- copy role: stream 8 state banks to output (bank 0 skips scratch prefix) ----
        long cid = (long)(bid / 5) * 4 + (bid % 5) - 1;   // 0..4095
        long tid = cid * 256 + t;
        {
            const nf4* s = (const nf4*)(s_I + PREFIX);
            float* d = o + PREFIX;
            for (long k = tid; k < BANK0_N4; k += COPY_THREADS) nt_copy4(s, k, d);
        }
        const float* srcs[7] = {s_T, b_I, b_T, u_I, u_T, tau_I, tau_T};
#pragma unroll
        for (int b = 0; b < 7; b++) {
            const nf4* s = (const nf4*)srcs[b];
            float* d = o + (long)(b + 1) * NSTATE;
            for (long k = tid; k < NSTATE / 4; k += COPY_THREADS) nt_copy4(s, k, d);
        }
        return;
    }

    // ---- GEMM role ----
    int gid = bid / 5;                 // 0..1023
    int by = gid >> 5, bx = gid & 31;
    int w = t >> 6, l = t & 63;
    int rw = w & 1, cw = w >> 1;
    int h = l >> 5, lc = l & 31;
    int rowbase = by * 128 + rw * 64;
    int colbase = bx * 128 + cw * 64;

    const u16* pAh = Ah + (size_t)(by * 4 + rw * 2) * 8192;
    const u16* pAl = Al + (size_t)(by * 4 + rw * 2) * 8192;
    const u16* pBh = Bh + (size_t)(bx * 4 + cw * 2) * 8192;
    const u16* pBl = Bl + (size_t)(bx * 4 + cw * 2) * 8192;

    f32x16 acc00, acc01, acc10, acc11;
#pragma unroll
    for (int e = 0; e < 16; ++e) { acc00[e] = 0.f; acc01[e] = 0.f; acc10[e] = 0.f; acc11[e] = 0.f; }

    for (int s = 0; s < 16; ++s) {
        int off = s * 512 + l * 8;
        short8 a0h = *(const short8*)(pAh + off);
        short8 a1h = *(const short8*)(pAh + 8192 + off);
        short8 a0l = *(const short8*)(pAl + off);
        short8 a1l = *(const short8*)(pAl + 8192 + off);
        short8 b0h = *(const short8*)(pBh + off);
        short8 b1h = *(const short8*)(pBh + 8192 + off);
        short8 b0l = *(const short8*)(pBl + off);
        short8 b1l = *(const short8*)(pBl + 8192 + off);

        acc00 = MFMA32(a0h, b0h, acc00, 0, 0, 0);
        acc01 = MFMA32(a0h, b1h, acc01, 0, 0, 0);
        acc10 = MFMA32(a1h, b0h, acc10, 0, 0, 0);
        acc11 = MFMA32(a1h, b1h, acc11, 0, 0, 0);
        acc00 = MFMA32(a0h, b0l, acc00, 0, 0, 0);
        acc01 = MFMA32(a0h, b1l, acc01, 0, 0, 0);
        acc10 = MFMA32(a1h, b0l, acc10, 0, 0, 0);
        acc11 = MFMA32(a1h, b1l, acc11, 0, 0, 0);
        acc00 = MFMA32(a0l, b0h, acc00, 0, 0, 0);
        acc01 = MFMA32(a0l, b1h, acc01, 0, 0, 0);
        acc10 = MFMA32(a1l, b0h, acc10, 0, 0, 0);
        acc11 = MFMA32(a1l, b1h, acc11, 0, 0, 0);
    }

    // ---- col partials (register path): C/D col = lane&31 ----
#define COLPART(A0, A1, CT) do {                                                   \
        int gc = colbase + (CT) * 32 + lc;                                         \
        float itc = colIT[gc];                                                     \
        float m = -INFINITY;                                                       \
        _Pragma("unroll") for (int e = 0; e < 16; ++e) {                           \
            m = fmaxf(m, (A0)[e]); m = fmaxf(m, (A1)[e]); }                        \
        m = fmaxf(m, __shfl_xor(m, 32));                                           \
        float S1 = 0.f, S2 = 0.f;                                                  \
        _Pragma("unroll") for (int e = 0; e < 16; ++e) {                           \
            float v0 = (A0)[e]; float e0 = __expf((v0 - m) * itc); S1 += e0; S2 += e0 * v0; \
            float v1 = (A1)[e]; float e1 = __expf((v1 - m) * itc); S1 += e1; S2 += e1 * v1; } \
        S1 += __shfl_xor(S1, 32); S2 += __shfl_xor(S2, 32);                        \
        if (h == 0) { int slot = by * 2 + rw;                                      \
            cPM [slot * 4096 + gc] = m;                                            \
            cPS1[slot * 4096 + gc] = S1;                                           \
            cPS2[slot * 4096 + gc] = S2; }                                         \
    } while (0)

    COLPART(acc00, acc10, 0);
    COLPART(acc01, acc11, 1);

    // ---- row partials via per-wave LDS transpose ----
#define ROWPART(TB) do {                                                           \
        float* Tb = (TB);                                                          \
        _Pragma("unroll") for (int q = 0; q < 4; ++q) {                            \
            _Pragma("unroll") for (int j = 0; j < 4; ++j) {                        \
                int rr = 8 * q + 4 * h + j;                                        \
                Tb[(rr     ) * 68 + lc     ] = acc00[4 * q + j];                   \
                Tb[(rr     ) * 68 + lc + 32] = acc01[4 * q + j];                   \
                Tb[(rr + 32) * 68 + lc     ] = acc10[4 * q + j];                   \
                Tb[(rr + 32) * 68 + lc + 32] = acc11[4 * q + j]; } }               \
        float itr = rowIT[rowbase + l];                                            \
        float4 vv[16];                                                             \
        _Pragma("unroll") for (int c = 0; c < 16; ++c)                             \
            vv[c] = *(const float4*)&Tb[l * 68 + 4 * c];                           \
        float m = -INFINITY;                                                       \
        _Pragma("unroll") for (int c = 0; c < 16; ++c)                             \
            m = fmaxf(m, fmaxf(fmaxf(vv[c].x, vv[c].y), fmaxf(vv[c].z, vv[c].w))); \
        float S1 = 0.f, S2 = 0.f;                                                  \
        _Pragma("unroll") for (int c = 0; c < 16; ++c) {                           \
            float e0 = __expf((vv[c].x - m) * itr); S1 += e0; S2 += e0 * vv[c].x;  \
            float e1 = __expf((vv[c].y - m) * itr); S1 += e1; S2 += e1 * vv[c].y;  \
            float e2 = __expf((vv[c].z - m) * itr); S1 += e2; S2 += e2 * vv[c].z;  \
            float e3 = __expf((vv[c].w - m) * itr); S1 += e3; S2 += e3 * vv[c].w; }\
        int slot = bx * 2 + cw;                                                    \
        rPM [slot * 4096 + rowbase + l] = m;                                       \
        rPS1[slot * 4096 + rowbase + l] = S1;                                      \
        rPS2[slot * 4096 + rowbase + l] = S2;                                      \
        if (bx == by && rw == cw) diag[rowbase + l] = Tb[l * 68 + l];              \
    } while (0)

    if (w < 2) ROWPART(T[w]);
    __syncthreads();
    if (w >= 2) ROWPART(T[w - 2]);
}

// ---------- K3: merge partials + full state math ----------
__global__ __launch_bounds__(256) void kmerge(
    const int* __restrict__ ids,
    const float* __restrict__ s_I, const float* __restrict__ b_I,
    const float* __restrict__ u_I, const float* __restrict__ tau_I,
    const float* __restrict__ s_T, const float* __restrict__ b_T,
    const float* __restrict__ u_T, const float* __restrict__ tau_T,
    const float* __restrict__ rowIT, const float* __restrict__ colIT,
    const float* __restrict__ diag,
    const float* __restrict__ rPM, const float* __restrict__ rPS1, const float* __restrict__ rPS2,
    const float* __restrict__ cPM, const float* __restrict__ cPS1, const float* __restrict__ cPS2,
    float* __restrict__ O,
    float* __restrict__ sc_arrs,
    float* __restrict__ img_loss_arr,
    float* __restrict__ txt_loss_arr)
{
    int j = blockIdx.x * 256 + threadIdx.x;
    if (j >= 2 * BDIM) return;
    bool rowside = (j < BDIM);
    int i = rowside ? j : j - BDIM;
    const float* PM  = rowside ? rPM  : cPM;
    const float* PS1 = rowside ? rPS1 : cPS1;
    const float* PS2 = rowside ? rPS2 : cPS2;
    float it = rowside ? rowIT[i] : colIT[i];

    float M = -INFINITY, S1 = 0.f, S2 = 0.f;
    for (int k = 0; k < 64; k++) {
        float m  = PM [k * BDIM + i];
        float s1 = PS1[k * BDIM + i];
        float s2 = PS2[k * BDIM + i];
        float Mn = fmaxf(M, m);
        float ea = __expf((M - Mn) * it);
        float eb = __expf((m - Mn) * it);
        S1 = S1 * ea + s1 * eb;
        S2 = S2 * ea + s2 * eb;
        M = Mn;
    }

    int id = ids[i];
    float tau  = rowside ? tau_I[id] : tau_T[id];
    float oldb = rowside ? b_I[id]   : b_T[id];
    float olds = rowside ? s_I[id]   : s_T[id];
    float oldu = rowside ? u_I[id]   : u_T[id];
    float dg = diag[i];

    float nb = fmaxf(oldb, (M - dg) * it);
    float F  = __expf((M - dg) * it - nb);
    float ed = __expf(-nb);                 // masked diagonal term
    float g  = F * S1 - ed;
    float Cs = F * (S2 - dg * S1);

    float s_new = (1.f - C_GAMMA_S) * olds * __expf(oldb - nb) + C_GAMMA_S * g;
    float sc = fmaxf(s_new, C_EPS);
    float loss = Cs / sc;
    float grad = logf(sc) + nb + C_RHO - (Cs / (sc * tau)) * (1.0f / (float)(BDIM - 1));
    float gc = fminf(fmaxf(grad, -C_GRAD_CLIP), C_GRAD_CLIP);
    float u_new = (1.f - C_GAMMA_U) * oldu + C_GAMMA_U * gc;
    float tau_new = fminf(fmaxf(tau - C_ETA * u_new, C_TAU_MIN), C_TAU_MAX);

    if (rowside) {
        O[i] = g;
        O[8192 + i] = grad;
        sc_arrs[0 * BDIM + i] = s_new;
        sc_arrs[1 * BDIM + i] = nb;
        sc_arrs[2 * BDIM + i] = u_new;
        sc_arrs[3 * BDIM + i] = tau_new;
        img_loss_arr[i] = loss;
    } else {
        O[4096 + i] = g;
        O[12288 + i] = grad;
        sc_arrs[4 * BDIM + i] = s_new;
        sc_arrs[5 * BDIM + i] = nb;
        sc_arrs[6 * BDIM + i] = u_new;
        sc_arrs[7 * BDIM + i] = tau_new;
        txt_loss_arr[i] = loss;
    }
}

// ---------- K4: copy bank-0 scratch prefix (now consumed) + scalar reductions ----------
__global__ __launch_bounds__(256) void kfix(const float* s_I, float* o,
                                            const float* img_loss_arr,
                                            const float* txt_loss_arr,
                                            const int* ids,
                                            const float* tau_I, const float* tau_T,
                                            float* O) {
    int bid = blockIdx.x;
    int t = threadIdx.x;
    if (bid < 3584) {
        long tid = (long)bid * 256 + t;
        const nf4* s = (const nf4*)s_I;
        for (long k = tid; k < PREFIX_N4; k += 3584L * 256) nt_copy4(s, k, o);
        return;
    }
    // scalars (single block)
    float s0 = 0.f, s1 = 0.f, s2 = 0.f, s3 = 0.f;
    for (int k = t; k < BDIM; k += 256) {
        s0 += img_loss_arr[k];
        s1 += txt_loss_arr[k];
        int id = ids[k];
        s2 += tau_I[id];
        s3 += tau_T[id];
    }
    __shared__ float r0[256], r1[256], r2[256], r3[256];
    r0[t] = s0; r1[t] = s1; r2[t] = s2; r3[t] = s3;
    __syncthreads();
    for (int s = 128; s > 0; s >>= 1) {
        if (t < s) {
            r0[t] += r0[t + s]; r1[t] += r1[t + s];
            r2[t] += r2[t + s]; r3[t] += r3[t + s];
        }
        __syncthreads();
    }
    if (t == 0) {
        float invB = 1.0f / (float)BDIM;
        O[16384] = C_ALPHA * (r0[0] * invB) + (1.f - C_ALPHA) * (r1[0] * invB);
        O[16385] = r2[0] * invB;
        O[16386] = r3[0] * invB;
    }
}

// ---------- K5: scatter updated state at ids (after ALL copies) ----------
__global__ __launch_bounds__(256) void kscat(const int* __restrict__ ids,
                                             const float* __restrict__ sc_arrs,
                                             float* __restrict__ o) {
    int t = blockIdx.x * 256 + threadIdx.x;
    if (t >= BDIM) return;
    long id = ids[t];
    o[0L * NSTATE + id] = sc_arrs[0 * BDIM + t];
    o[1L * NSTATE + id] = sc_arrs[4 * BDIM + t];
    o[2L * NSTATE + id] = sc_arrs[1 * BDIM + t];
    o[3L * NSTATE + id] = sc_arrs[5 * BDIM + t];
    o[4L * NSTATE + id] = sc_arrs[2 * BDIM + t];
    o[5L * NSTATE + id] = sc_arrs[6 * BDIM + t];
    o[6L * NSTATE + id] = sc_arrs[3 * BDIM + t];
    o[7L * NSTATE + id] = sc_arrs[7 * BDIM + t];
}

extern "C" void kernel_launch(void* const* d_in, const int* in_sizes, int n_in,
                              void* d_out, int out_size, void* d_ws, size_t ws_size,
                              hipStream_t stream) {
    const float* zis   = (const float*)d_in[0];
    const float* zjs   = (const float*)d_in[1];
    const int*   ids   = (const int*)d_in[2];
    const float* s_I   = (const float*)d_in[3];
    const float* s_T   = (const float*)d_in[4];
    const float* b_I   = (const float*)d_in[5];
    const float* b_T   = (const float*)d_in[6];
    const float* u_I   = (const float*)d_in[7];
    const float* u_T   = (const float*)d_in[8];
    const float* tau_I = (const float*)d_in[9];
    const float* tau_T = (const float*)d_in[10];
    float* O  = (float*)d_out;
    float* ws = (float*)d_ws;

    // scratch in d_out's bank-0 prefix (consumed by kmerge, then restored by kfix)
    float* P = O + 16388;                       // 16B-aligned
    float* rPM  = P;                            // 64*4096 each
    float* rPS1 = P + 262144;
    float* rPS2 = P + 524288;
    float* cPM  = P + 786432;
    float* cPS1 = P + 1048576;
    float* cPS2 = P + 1310720;
    float* diag = P + 1572864;                  // 4096
    u16* AB = (u16*)(P + 1576960);              // 4 x 1,048,576 bf16
    u16* Ah = AB;
    u16* Al = AB + 1048576;
    u16* Bh = AB + 2097152;
    u16* Bl = AB + 3145728;

    // small arrays in ws
    float* rowIT  = ws;                         // 4096 each
    float* colIT  = ws + 4096;
    float* sc_arrs = ws + 8192;                 // 8 x 4096
    float* img_loss_arr = ws + 40960;
    float* txt_loss_arr = ws + 45056;

    kprep<<<257, 256, 0, stream>>>(zis, zjs, Ah, Al, Bh, Bl,
                                   ids, tau_I, tau_T, rowIT, colIT);

    kmain<<<5120, 256, 0, stream>>>(Ah, Al, Bh, Bl, rowIT, colIT,
                                    rPM, rPS1, rPS2, cPM, cPS1, cPS2, diag,
                                    s_I, s_T, b_I, b_T, u_I, u_T, tau_I, tau_T,
                                    O + 16387);

    kmerge<<<32, 256, 0, stream>>>(ids, s_I, b_I, u_I, tau_I, s_T, b_T, u_T, tau_T,
                                   rowIT, colIT, diag,
                                   rPM, rPS1, rPS2, cPM, cPS1, cPS2,
                                   O, sc_arrs, img_loss_arr, txt_loss_arr);

    kfix<<<3585, 256, 0, stream>>>(s_I, O + 16387, img_loss_arr, txt_loss_arr,
                                   ids, tau_I, tau_T, O);

    kscat<<<16, 256, 0, stream>>>(ids, sc_arrs, O + 16387);
}

// Round 6
// 547.187 us; speedup vs baseline: 1.3171x; 1.0095x over previous
//
#include <hip/hip_runtime.h>
#include <math.h>

#define BDIM 4096
#define DDIM 256
#define NSTATE 9000000
// fallback (small-ws) scheme: bank-0 prefix holding live scratch, copied late:
#define PREFIX 3674116
#define PREFIX_N4 918529     // PREFIX / 4
#define COPY_THREADS 1048576 // 4096 copy blocks * 256

#define C_ALPHA 0.5f
#define C_GAMMA_S 0.8f
#define C_GAMMA_U 0.9f
#define C_RHO 6.0f
#define C_EPS 1e-14f
#define C_ETA 0.01f
#define C_TAU_MIN 0.001f
#define C_TAU_MAX 1.0f
#define C_GRAD_CLIP 5.0f

typedef unsigned short u16;
typedef __attribute__((ext_vector_type(8))) short short8;
typedef __attribute__((ext_vector_type(16))) float f32x16;
typedef __attribute__((ext_vector_type(4))) float nf4;

#define MFMA32 __builtin_amdgcn_mfma_f32_32x32x16_bf16

__device__ inline u16 f2bf(float f) {
    unsigned u = __float_as_uint(f);
    unsigned r = (u + 0x7FFFu + ((u >> 16) & 1u)) >> 16;
    return (u16)r;
}
__device__ inline float bf2f(u16 h) { return __uint_as_float(((unsigned)h) << 16); }

__device__ inline void nt_copy4(const nf4* __restrict__ s, long k, float* __restrict__ dbase) {
    nf4 v = __builtin_nontemporal_load(&s[k]);
    float* dp = dbase + 4 * k;
    __builtin_nontemporal_store(v.x, dp + 0);
    __builtin_nontemporal_store(v.y, dp + 1);
    __builtin_nontemporal_store(v.z, dp + 2);
    __builtin_nontemporal_store(v.w, dp + 3);
}

// ---------- K1: normalize + split to bf16 hi/lo in MFMA-fragment layout; block 256 does 1/tau ----------
__global__ __launch_bounds__(256) void kprep(const float* __restrict__ zis,
                                             const float* __restrict__ zjs,
                                             u16* __restrict__ Ah, u16* __restrict__ Al,
                                             u16* __restrict__ Bh, u16* __restrict__ Bl,
                                             const int* __restrict__ ids,
                                             const float* __restrict__ tau_I,
                                             const float* __restrict__ tau_T,
                                             float* __restrict__ rowIT,
                                             float* __restrict__ colIT) {
    int blk = blockIdx.x;                 // 0..256
    int t = threadIdx.x;
    if (blk == 256) {
        for (int i = t; i < BDIM; i += 256) {
            int id = ids[i];
            rowIT[i] = 1.0f / tau_I[id];
            colIT[i] = 1.0f / tau_T[id];
        }
        return;
    }
    bool isB = blk >= 128;
    const float* Z = isB ? zjs : zis;
    u16* H = isB ? Bh : Ah;
    u16* L = isB ? Bl : Al;
    int rblk = blk & 127;
    int r = t & 31, kc0 = t >> 5;         // 8 threads per row
    int row = rblk * 32 + r;

    __shared__ float ssq[32];
    if (t < 32) ssq[t] = 0.f;
    __syncthreads();

    float4 v[8];
    float partial = 0.f;
#pragma unroll
    for (int c = 0; c < 4; ++c) {
        int kc = kc0 + 8 * c;
        float4 a = *(const float4*)&Z[(size_t)row * DDIM + kc * 8];
        float4 b = *(const float4*)&Z[(size_t)row * DDIM + kc * 8 + 4];
        v[2 * c] = a; v[2 * c + 1] = b;
        partial += a.x * a.x + a.y * a.y + a.z * a.z + a.w * a.w;
        partial += b.x * b.x + b.y * b.y + b.z * b.z + b.w * b.w;
    }
    atomicAdd(&ssq[r], partial);
    __syncthreads();
    float inv = rsqrtf(ssq[r]);

#pragma unroll
    for (int c = 0; c < 4; ++c) {
        int kc = kc0 + 8 * c;
        float f[8];
        f[0] = v[2*c].x * inv;   f[1] = v[2*c].y * inv;
        f[2] = v[2*c].z * inv;   f[3] = v[2*c].w * inv;
        f[4] = v[2*c+1].x * inv; f[5] = v[2*c+1].y * inv;
        f[6] = v[2*c+1].z * inv; f[7] = v[2*c+1].w * inv;
        u16 hh[8], ll[8];
#pragma unroll
        for (int j = 0; j < 8; ++j) {
            hh[j] = f2bf(f[j]);
            ll[j] = f2bf(f[j] - bf2f(hh[j]));
        }
        size_t base = (size_t)rblk * 8192 + (size_t)kc * 256 + (size_t)r * 8;
        uint4 ph, pl;
        ph.x = (unsigned)hh[0] | ((unsigned)hh[1] << 16);
        ph.y = (unsigned)hh[2] | ((unsigned)hh[3] << 16);
        ph.z = (unsigned)hh[4] | ((unsigned)hh[5] << 16);
        ph.w = (unsigned)hh[6] | ((unsigned)hh[7] << 16);
        pl.x = (unsigned)ll[0] | ((unsigned)ll[1] << 16);
        pl.y = (unsigned)ll[2] | ((unsigned)ll[3] << 16);
        pl.z = (unsigned)ll[4] | ((unsigned)ll[5] << 16);
        pl.w = (unsigned)ll[6] | ((unsigned)ll[7] << 16);
        *(uint4*)(H + base) = ph;
        *(uint4*)(L + base) = pl;
    }
}

// ---------- K2: fused MFMA GEMM (1024 blocks) + nontemporal state copy (4096 blocks) ----------
// b0s: element offset into bank 0 where the copy starts (0 in big-ws path,
//      PREFIX in fallback path where scratch lives in d_out's prefix).
__global__ __launch_bounds__(256, 3) void kmain(
    const u16* __restrict__ Ah, const u16* __restrict__ Al,
    const u16* __restrict__ Bh, const u16* __restrict__ Bl,
    const float* __restrict__ rowIT, const float* __restrict__ colIT,
    float* __restrict__ rPM, float* __restrict__ rPS1, float* __restrict__ rPS2,
    float* __restrict__ cPM, float* __restrict__ cPS1, float* __restrict__ cPS2,
    float* __restrict__ diag,
    const float* __restrict__ s_I, const float* __restrict__ s_T,
    const float* __restrict__ b_I, const float* __restrict__ b_T,
    const float* __restrict__ u_I, const float* __restrict__ u_T,
    const float* __restrict__ tau_I, const float* __restrict__ tau_T,
    long b0s, float* o)
{
    __shared__ float T[2][64 * 68];
    int bid = blockIdx.x;
    int t = threadIdx.x;

    if (bid % 5 != 0) {
        // ---- copy role: stream 8 state banks to output ----
        long cid = (long)(bid / 5) * 4 + (bid % 5) - 1;   // 0..4095
        long tid = cid * 256 + t;
        {
            const nf4* s = (const nf4*)(s_I + b0s);
            float* d = o + b0s;
            long n4 = (NSTATE - b0s) / 4;
            for (long k = tid; k < n4; k += COPY_THREADS) nt_copy4(s, k, d);
        }
        const float* srcs[7] = {s_T, b_I, b_T, u_I, u_T, tau_I, tau_T};
#pragma unroll
        for (int b = 0; b < 7; b++) {
            const nf4* s = (const nf4*)srcs[b];
            float* d = o + (long)(b + 1) * NSTATE;
            for (long k = tid; k < NSTATE / 4; k += COPY_THREADS) nt_copy4(s, k, d);
        }
        return;
    }

    // ---- GEMM role ----
    int gid = bid / 5;                 // 0..1023
    int by = gid >> 5, bx = gid & 31;
    int w = t >> 6, l = t & 63;
    int rw = w & 1, cw = w >> 1;
    int h = l >> 5, lc = l & 31;
    int rowbase = by * 128 + rw * 64;
    int colbase = bx * 128 + cw * 64;

    const u16* pAh = Ah + (size_t)(by * 4 + rw * 2) * 8192;
    const u16* pAl = Al + (size_t)(by * 4 + rw * 2) * 8192;
    const u16* pBh = Bh + (size_t)(bx * 4 + cw * 2) * 8192;
    const u16* pBl = Bl + (size_t)(bx * 4 + cw * 2) * 8192;

    f32x16 acc00, acc01, acc10, acc11;
#pragma unroll
    for (int e = 0; e < 16; ++e) { acc00[e] = 0.f; acc01[e] = 0.f; acc10[e] = 0.f; acc11[e] = 0.f; }

    for (int s = 0; s < 16; ++s) {
        int off = s * 512 + l * 8;
        short8 a0h = *(const short8*)(pAh + off);
        short8 a1h = *(const short8*)(pAh + 8192 + off);
        short8 a0l = *(const short8*)(pAl + off);
        short8 a1l = *(const short8*)(pAl + 8192 + off);
        short8 b0h = *(const short8*)(pBh + off);
        short8 b1h = *(const short8*)(pBh + 8192 + off);
        short8 b0l = *(const short8*)(pBl + off);
        short8 b1l = *(const short8*)(pBl + 8192 + off);

        acc00 = MFMA32(a0h, b0h, acc00, 0, 0, 0);
        acc01 = MFMA32(a0h, b1h, acc01, 0, 0, 0);
        acc10 = MFMA32(a1h, b0h, acc10, 0, 0, 0);
        acc11 = MFMA32(a1h, b1h, acc11, 0, 0, 0);
        acc00 = MFMA32(a0h, b0l, acc00, 0, 0, 0);
        acc01 = MFMA32(a0h, b1l, acc01, 0, 0, 0);
        acc10 = MFMA32(a1h, b0l, acc10, 0, 0, 0);
        acc11 = MFMA32(a1h, b1l, acc11, 0, 0, 0);
        acc00 = MFMA32(a0l, b0h, acc00, 0, 0, 0);
        acc01 = MFMA32(a0l, b1h, acc01, 0, 0, 0);
        acc10 = MFMA32(a1l, b0h, acc10, 0, 0, 0);
        acc11 = MFMA32(a1l, b1h, acc11, 0, 0, 0);
    }

    // ---- col partials (register path): C/D col = lane&31 ----
#define COLPART(A0, A1, CT) do {                                                   \
        int gc = colbase + (CT) * 32 + lc;                                         \
        float itc = colIT[gc];                                                     \
        float m = -INFINITY;                                                       \
        _Pragma("unroll") for (int e = 0; e < 16; ++e) {                           \
            m = fmaxf(m, (A0)[e]); m = fmaxf(m, (A1)[e]); }                        \
        m = fmaxf(m, __shfl_xor(m, 32));                                           \
        float S1 = 0.f, S2 = 0.f;                                                  \
        _Pragma("unroll") for (int e = 0; e < 16; ++e) {                           \
            float v0 = (A0)[e]; float e0 = __expf((v0 - m) * itc); S1 += e0; S2 += e0 * v0; \
            float v1 = (A1)[e]; float e1 = __expf((v1 - m) * itc); S1 += e1; S2 += e1 * v1; } \
        S1 += __shfl_xor(S1, 32); S2 += __shfl_xor(S2, 32);                        \
        if (h == 0) { int slot = by * 2 + rw;                                      \
            cPM [slot * 4096 + gc] = m;                                            \
            cPS1[slot * 4096 + gc] = S1;                                           \
            cPS2[slot * 4096 + gc] = S2; }                                         \
    } while (0)

    COLPART(acc00, acc10, 0);
    COLPART(acc01, acc11, 1);

    // ---- row partials via per-wave LDS transpose ----
#define ROWPART(TB) do {                                                           \
        float* Tb = (TB);                                                          \
        _Pragma("unroll") for (int q = 0; q < 4; ++q) {                            \
            _Pragma("unroll") for (int j = 0; j < 4; ++j) {                        \
                int rr = 8 * q + 4 * h + j;                                        \
                Tb[(rr     ) * 68 + lc     ] = acc00[4 * q + j];                   \
                Tb[(rr     ) * 68 + lc + 32] = acc01[4 * q + j];                   \
                Tb[(rr + 32) * 68 + lc     ] = acc10[4 * q + j];                   \
                Tb[(rr + 32) * 68 + lc + 32] = acc11[4 * q + j]; } }               \
        float itr = rowIT[rowbase + l];                                            \
        float4 vv[16];                                                             \
        _Pragma("unroll") for (int c = 0; c < 16; ++c)                             \
            vv[c] = *(const float4*)&Tb[l * 68 + 4 * c];                           \
        float m = -INFINITY;                                                       \
        _Pragma("unroll") for (int c = 0; c < 16; ++c)                             \
            m = fmaxf(m, fmaxf(fmaxf(vv[c].x, vv[c].y), fmaxf(vv[c].z, vv[c].w))); \
        float S1 = 0.f, S2 = 0.f;                                                  \
        _Pragma("unroll") for (int c = 0; c < 16; ++c) {                           \
            float e0 = __expf((vv[c].x - m) * itr); S1 += e0; S2 += e0 * vv[c].x;  \
            float e1 = __expf((vv[c].y - m) * itr); S1 += e1; S2 += e1 * vv[c].y;  \
            float e2 = __expf((vv[c].z - m) * itr); S1 += e2; S2 += e2 * vv[c].z;  \
            float e3 = __expf((vv[c].w - m) * itr); S1 += e3; S2 += e3 * vv[c].w; }\
        int slot = bx * 2 + cw;                                                    \
        rPM [slot * 4096 + rowbase + l] = m;                                       \
        rPS1[slot * 4096 + rowbase + l] = S1;                                      \
        rPS2[slot * 4096 + rowbase + l] = S2;                                      \
        if (bx == by && rw == cw) diag[rowbase + l] = Tb[l * 68 + l];              \
    } while (0)

    if (w < 2) ROWPART(T[w]);
    __syncthreads();
    if (w >= 2) ROWPART(T[w - 2]);
}

// ---------- K3: merge partials + full state math (+ optional inline scatter) ----------
__global__ __launch_bounds__(256) void kmerge(
    const int* __restrict__ ids,
    const float* __restrict__ s_I, const float* __restrict__ b_I,
    const float* __restrict__ u_I, const float* __restrict__ tau_I,
    const float* __restrict__ s_T, const float* __restrict__ b_T,
    const float* __restrict__ u_T, const float* __restrict__ tau_T,
    const float* __restrict__ rowIT, const float* __restrict__ colIT,
    const float* __restrict__ diag,
    const float* __restrict__ rPM, const float* __restrict__ rPS1, const float* __restrict__ rPS2,
    const float* __restrict__ cPM, const float* __restrict__ cPS1, const float* __restrict__ cPS2,
    float* __restrict__ O,
    float* __restrict__ sc_arrs,     // fallback path (o_scat == nullptr)
    float* o_scat,                   // big-ws path: scatter directly into output state
    float* __restrict__ img_loss_arr,
    float* __restrict__ txt_loss_arr)
{
    int j = blockIdx.x * 256 + threadIdx.x;
    if (j >= 2 * BDIM) return;
    bool rowside = (j < BDIM);
    int i = rowside ? j : j - BDIM;
    const float* PM  = rowside ? rPM  : cPM;
    const float* PS1 = rowside ? rPS1 : cPS1;
    const float* PS2 = rowside ? rPS2 : cPS2;
    float it = rowside ? rowIT[i] : colIT[i];

    float M = -INFINITY, S1 = 0.f, S2 = 0.f;
    for (int k = 0; k < 64; k++) {
        float m  = PM [k * BDIM + i];
        float s1 = PS1[k * BDIM + i];
        float s2 = PS2[k * BDIM + i];
        float Mn = fmaxf(M, m);
        float ea = __expf((M - Mn) * it);
        float eb = __expf((m - Mn) * it);
        S1 = S1 * ea + s1 * eb;
        S2 = S2 * ea + s2 * eb;
        M = Mn;
    }

    int id = ids[i];
    float tau  = rowside ? tau_I[id] : tau_T[id];
    float oldb = rowside ? b_I[id]   : b_T[id];
    float olds = rowside ? s_I[id]   : s_T[id];
    float oldu = rowside ? u_I[id]   : u_T[id];
    float dg = diag[i];

    float nb = fmaxf(oldb, (M - dg) * it);
    float F  = __expf((M - dg) * it - nb);
    float ed = __expf(-nb);                 // masked diagonal term
    float g  = F * S1 - ed;
    float Cs = F * (S2 - dg * S1);

    float s_new = (1.f - C_GAMMA_S) * olds * __expf(oldb - nb) + C_GAMMA_S * g;
    float sc = fmaxf(s_new, C_EPS);
    float loss = Cs / sc;
    float grad = logf(sc) + nb + C_RHO - (Cs / (sc * tau)) * (1.0f / (float)(BDIM - 1));
    float gc = fminf(fmaxf(grad, -C_GRAD_CLIP), C_GRAD_CLIP);
    float u_new = (1.f - C_GAMMA_U) * oldu + C_GAMMA_U * gc;
    float tau_new = fminf(fmaxf(tau - C_ETA * u_new, C_TAU_MIN), C_TAU_MAX);

    int bank0 = rowside ? 0 : 1;   // s, then b(+2), u(+4), tau(+6)
    if (rowside) {
        O[i] = g;
        O[8192 + i] = grad;
        img_loss_arr[i] = loss;
    } else {
        O[4096 + i] = g;
        O[12288 + i] = grad;
        txt_loss_arr[i] = loss;
    }
    if (o_scat) {
        long lid = id;
        o_scat[(long)(bank0 + 0) * NSTATE + lid] = s_new;
        o_scat[(long)(bank0 + 2) * NSTATE + lid] = nb;
        o_scat[(long)(bank0 + 4) * NSTATE + lid] = u_new;
        o_scat[(long)(bank0 + 6) * NSTATE + lid] = tau_new;
    } else {
        int base = rowside ? 0 : 4;
        sc_arrs[(base + 0) * BDIM + i] = s_new;
        sc_arrs[(base + 1) * BDIM + i] = nb;
        sc_arrs[(base + 2) * BDIM + i] = u_new;
        sc_arrs[(base + 3) * BDIM + i] = tau_new;
    }
}

// ---------- K4a (big-ws): scalars only ----------
__global__ __launch_bounds__(256) void kscal(const float* __restrict__ img_loss_arr,
                                             const float* __restrict__ txt_loss_arr,
                                             const int* __restrict__ ids,
                                             const float* __restrict__ tau_I,
                                             const float* __restrict__ tau_T,
                                             float* __restrict__ O) {
    int t = threadIdx.x;
    float s0 = 0.f, s1 = 0.f, s2 = 0.f, s3 = 0.f;
    for (int k = t; k < BDIM; k += 256) {
        s0 += img_loss_arr[k];
        s1 += txt_loss_arr[k];
        int id = ids[k];
        s2 += tau_I[id];
        s3 += tau_T[id];
    }
    __shared__ float r0[256], r1[256], r2[256], r3[256];
    r0[t] = s0; r1[t] = s1; r2[t] = s2; r3[t] = s3;
    __syncthreads();
    for (int s = 128; s > 0; s >>= 1) {
        if (t < s) {
            r0[t] += r0[t + s]; r1[t] += r1[t + s];
            r2[t] += r2[t + s]; r3[t] += r3[t + s];
        }
        __syncthreads();
    }
    if (t == 0) {
        float invB = 1.0f / (float)BDIM;
        O[16384] = C_ALPHA * (r0[0] * invB) + (1.f - C_ALPHA) * (r1[0] * invB);
        O[16385] = r2[0] * invB;
        O[16386] = r3[0] * invB;
    }
}

// ---------- K4b (fallback): prefix copy + scalars ----------
__global__ __launch_bounds__(256) void kfix(const float* s_I, float* o,
                                            const float* img_loss_arr,
                                            const float* txt_loss_arr,
                                            const int* ids,
                                            const float* tau_I, const float* tau_T,
                                            float* O) {
    int bid = blockIdx.x;
    int t = threadIdx.x;
    if (bid < 3584) {
        long tid = (long)bid * 256 + t;
        const nf4* s = (const nf4*)s_I;
        for (long k = tid; k < PREFIX_N4; k += 3584L * 256) nt_copy4(s, k, o);
        return;
    }
    float s0 = 0.f, s1 = 0.f, s2 = 0.f, s3 = 0.f;
    for (int k = t; k < BDIM; k += 256) {
        s0 += img_loss_arr[k];
        s1 += txt_loss_arr[k];
        int id = ids[k];
        s2 += tau_I[id];
        s3 += tau_T[id];
    }
    __shared__ float r0[256], r1[256], r2[256], r3[256];
    r0[t] = s0; r1[t] = s1; r2[t] = s2; r3[t] = s3;
    __syncthreads();
    for (int s = 128; s > 0; s >>= 1) {
        if (t < s) {
            r0[t] += r0[t + s]; r1[t] += r1[t + s];
            r2[t] += r2[t + s]; r3[t] += r3[t + s];
        }
        __syncthreads();
    }
    if (t == 0) {
        float invB = 1.0f / (float)BDIM;
        O[16384] = C_ALPHA * (r0[0] * invB) + (1.f - C_ALPHA) * (r1[0] * invB);
        O[16385] = r2[0] * invB;
        O[16386] = r3[0] * invB;
    }
}

// ---------- K5 (fallback): scatter updated state at ids ----------
__global__ __launch_bounds__(256) void kscat(const int* __restrict__ ids,
                                             const float* __restrict__ sc_arrs,
                                             float* __restrict__ o) {
    int t = blockIdx.x * 256 + threadIdx.x;
    if (t >= BDIM) return;
    long id = ids[t];
    o[0L * NSTATE + id] = sc_arrs[0 * BDIM + t];
    o[1L * NSTATE + id] = sc_arrs[4 * BDIM + t];
    o[2L * NSTATE + id] = sc_arrs[1 * BDIM + t];
    o[3L * NSTATE + id] = sc_arrs[5 * BDIM + t];
    o[4L * NSTATE + id] = sc_arrs[2 * BDIM + t];
    o[5L * NSTATE + id] = sc_arrs[6 * BDIM + t];
    o[6L * NSTATE + id] = sc_arrs[3 * BDIM + t];
    o[7L * NSTATE + id] = sc_arrs[7 * BDIM + t];
}

extern "C" void kernel_launch(void* const* d_in, const int* in_sizes, int n_in,
                              void* d_out, int out_size, void* d_ws, size_t ws_size,
                              hipStream_t stream) {
    const float* zis   = (const float*)d_in[0];
    const float* zjs   = (const float*)d_in[1];
    const int*   ids   = (const int*)d_in[2];
    const float* s_I   = (const float*)d_in[3];
    const float* s_T   = (const float*)d_in[4];
    const float* b_I   = (const float*)d_in[5];
    const float* b_T   = (const float*)d_in[6];
    const float* u_I   = (const float*)d_in[7];
    const float* u_T   = (const float*)d_in[8];
    const float* tau_I = (const float*)d_in[9];
    const float* tau_T = (const float*)d_in[10];
    float* O  = (float*)d_out;
    float* ws = (float*)d_ws;

    // small arrays always in ws
    float* rowIT  = ws;                         // 4096 each
    float* colIT  = ws + 4096;
    float* img_loss_arr = ws + 8192;
    float* txt_loss_arr = ws + 12288;
    float* sc_arrs = ws + 16384;                // 8 x 4096 (fallback only)

    const bool bigws = ws_size >= (size_t)16 * 1024 * 1024;

    float *rPM, *rPS1, *rPS2, *cPM, *cPS1, *cPS2, *diag;
    u16 *Ah, *Al, *Bh, *Bl;
    long b0s;
    if (bigws) {
        float* P = ws + 53248;                  // big scratch in d_ws
        rPM  = P;            rPS1 = P + 262144;  rPS2 = P + 524288;
        cPM  = P + 786432;   cPS1 = P + 1048576; cPS2 = P + 1310720;
        diag = P + 1572864;
        Ah = (u16*)(P + 1576960);
        Al = Ah + 1048576; Bh = Al + 1048576; Bl = Bh + 1048576;
        b0s = 0;
    } else {
        float* P = O + 16388;                   // fallback: d_out bank-0 prefix
        rPM  = P;            rPS1 = P + 262144;  rPS2 = P + 524288;
        cPM  = P + 786432;   cPS1 = P + 1048576; cPS2 = P + 1310720;
        diag = P + 1572864;
        Ah = (u16*)(P + 1576960);
        Al = Ah + 1048576; Bh = Al + 1048576; Bl = Bh + 1048576;
        b0s = PREFIX;
    }

    kprep<<<257, 256, 0, stream>>>(zis, zjs, Ah, Al, Bh, Bl,
                                   ids, tau_I, tau_T, rowIT, colIT);

    kmain<<<5120, 256, 0, stream>>>(Ah, Al, Bh, Bl, rowIT, colIT,
                                    rPM, rPS1, rPS2, cPM, cPS1, cPS2, diag,
                                    s_I, s_T, b_I, b_T, u_I, u_T, tau_I, tau_T,
                                    b0s, O + 16387);

    kmerge<<<32, 256, 0, stream>>>(ids, s_I, b_I, u_I, tau_I, s_T, b_T, u_T, tau_T,
                                   rowIT, colIT, diag,
                                   rPM, rPS1, rPS2, cPM, cPS1, cPS2,
                                   O, sc_arrs, bigws ? (O + 16387) : nullptr,
                                   img_loss_arr, txt_loss_arr);

    if (bigws) {
        kscal<<<1, 256, 0, stream>>>(img_loss_arr, txt_loss_arr, ids, tau_I, tau_T, O);
    } else {
        kfix<<<3585, 256, 0, stream>>>(s_I, O + 16387, img_loss_arr, txt_loss_arr,
                                       ids, tau_I, tau_T, O);
        kscat<<<16, 256, 0, stream>>>(ids, sc_arrs, O + 16387);
    }
}

// Round 9
// 544.168 us; speedup vs baseline: 1.3244x; 1.0055x over previous
//
#include <hip/hip_runtime.h>
#include <math.h>

#define BDIM 4096
#define DDIM 256
#define NSTATE 9000000
// fallback (small-ws) scheme: bank-0 prefix holding live scratch, copied late:
#define PREFIX 3674116
#define PREFIX_N4 918529     // PREFIX / 4
#define COPY_THREADS 1048576 // 4096 copy blocks * 256

#define C_ALPHA 0.5f
#define C_GAMMA_S 0.8f
#define C_GAMMA_U 0.9f
#define C_RHO 6.0f
#define C_EPS 1e-14f
#define C_ETA 0.01f
#define C_TAU_MIN 0.001f
#define C_TAU_MAX 1.0f
#define C_GRAD_CLIP 5.0f

typedef unsigned short u16;
typedef __attribute__((ext_vector_type(8))) short short8;
typedef __attribute__((ext_vector_type(16))) float f32x16;
typedef __attribute__((ext_vector_type(4))) float nf4;

#define MFMA32 __builtin_amdgcn_mfma_f32_32x32x16_bf16

__device__ inline u16 f2bf(float f) {
    unsigned u = __float_as_uint(f);
    unsigned r = (u + 0x7FFFu + ((u >> 16) & 1u)) >> 16;
    return (u16)r;
}
__device__ inline float bf2f(u16 h) { return __uint_as_float(((unsigned)h) << 16); }

__device__ inline void nt_copy4(const nf4* __restrict__ s, long k, float* __restrict__ dbase) {
    nf4 v = __builtin_nontemporal_load(&s[k]);
    float* dp = dbase + 4 * k;
    __builtin_nontemporal_store(v.x, dp + 0);
    __builtin_nontemporal_store(v.y, dp + 1);
    __builtin_nontemporal_store(v.z, dp + 2);
    __builtin_nontemporal_store(v.w, dp + 3);
}

// ---------- K1: normalize + split to bf16 hi/lo in MFMA-fragment layout ----------
// block 256: 1/tau, tau sums, and reset of loss accumulators + ticket.
__global__ __launch_bounds__(256) void kprep(const float* __restrict__ zis,
                                             const float* __restrict__ zjs,
                                             u16* __restrict__ Ah, u16* __restrict__ Al,
                                             u16* __restrict__ Bh, u16* __restrict__ Bl,
                                             const int* __restrict__ ids,
                                             const float* __restrict__ tau_I,
                                             const float* __restrict__ tau_T,
                                             float* __restrict__ rowIT,
                                             float* __restrict__ colIT,
                                             float* __restrict__ acc4,
                                             int* __restrict__ ticket) {
    int blk = blockIdx.x;                 // 0..256
    int t = threadIdx.x;
    if (blk == 256) {
        float sI = 0.f, sT = 0.f;
        for (int i = t; i < BDIM; i += 256) {
            int id = ids[i];
            float ti = tau_I[id], tt = tau_T[id];
            rowIT[i] = 1.0f / ti;
            colIT[i] = 1.0f / tt;
            sI += ti; sT += tt;
        }
        __shared__ float red[512];
        red[t] = sI; red[256 + t] = sT;
        __syncthreads();
        for (int s = 128; s > 0; s >>= 1) {
            if (t < s) { red[t] += red[t + s]; red[256 + t] += red[256 + t + s]; }
            __syncthreads();
        }
        if (t == 0) {
            acc4[0] = 0.f;        // loss_I accumulator
            acc4[1] = 0.f;        // loss_T accumulator
            acc4[2] = red[0];     // sum tau_I
            acc4[3] = red[256];   // sum tau_T
            *ticket = 0;
        }
        return;
    }
    bool isB = blk >= 128;
    const float* Z = isB ? zjs : zis;
    u16* H = isB ? Bh : Ah;
    u16* L = isB ? Bl : Al;
    int rblk = blk & 127;
    int r = t & 31, kc0 = t >> 5;         // 8 threads per row
    int row = rblk * 32 + r;

    __shared__ float ssq[32];
    if (t < 32) ssq[t] = 0.f;
    __syncthreads();

    float4 v[8];
    float partial = 0.f;
#pragma unroll
    for (int c = 0; c < 4; ++c) {
        int kc = kc0 + 8 * c;
        float4 a = *(const float4*)&Z[(size_t)row * DDIM + kc * 8];
        float4 b = *(const float4*)&Z[(size_t)row * DDIM + kc * 8 + 4];
        v[2 * c] = a; v[2 * c + 1] = b;
        partial += a.x * a.x + a.y * a.y + a.z * a.z + a.w * a.w;
        partial += b.x * b.x + b.y * b.y + b.z * b.z + b.w * b.w;
    }
    atomicAdd(&ssq[r], partial);
    __syncthreads();
    float inv = rsqrtf(ssq[r]);

#pragma unroll
    for (int c = 0; c < 4; ++c) {
        int kc = kc0 + 8 * c;
        float f[8];
        f[0] = v[2*c].x * inv;   f[1] = v[2*c].y * inv;
        f[2] = v[2*c].z * inv;   f[3] = v[2*c].w * inv;
        f[4] = v[2*c+1].x * inv; f[5] = v[2*c+1].y * inv;
        f[6] = v[2*c+1].z * inv; f[7] = v[2*c+1].w * inv;
        u16 hh[8], ll[8];
#pragma unroll
        for (int j = 0; j < 8; ++j) {
            hh[j] = f2bf(f[j]);
            ll[j] = f2bf(f[j] - bf2f(hh[j]));
        }
        size_t base = (size_t)rblk * 8192 + (size_t)kc * 256 + (size_t)r * 8;
        uint4 ph, pl;
        ph.x = (unsigned)hh[0] | ((unsigned)hh[1] << 16);
        ph.y = (unsigned)hh[2] | ((unsigned)hh[3] << 16);
        ph.z = (unsigned)hh[4] | ((unsigned)hh[5] << 16);
        ph.w = (unsigned)hh[6] | ((unsigned)hh[7] << 16);
        pl.x = (unsigned)ll[0] | ((unsigned)ll[1] << 16);
        pl.y = (unsigned)ll[2] | ((unsigned)ll[3] << 16);
        pl.z = (unsigned)ll[4] | ((unsigned)ll[5] << 16);
        pl.w = (unsigned)ll[6] | ((unsigned)ll[7] << 16);
        *(uint4*)(H + base) = ph;
        *(uint4*)(L + base) = pl;
    }
}

// ---------- K2: fused MFMA GEMM (1024 blocks) + nontemporal state copy (4096 blocks) ----------
__global__ __launch_bounds__(256, 3) void kmain(
    const u16* __restrict__ Ah, const u16* __restrict__ Al,
    const u16* __restrict__ Bh, const u16* __restrict__ Bl,
    const float* __restrict__ rowIT, const float* __restrict__ colIT,
    float* __restrict__ rPM, float* __restrict__ rPS1, float* __restrict__ rPS2,
    float* __restrict__ cPM, float* __restrict__ cPS1, float* __restrict__ cPS2,
    float* __restrict__ diag,
    const float* __restrict__ s_I, const float* __restrict__ s_T,
    const float* __restrict__ b_I, const float* __restrict__ b_T,
    const float* __restrict__ u_I, const float* __restrict__ u_T,
    const float* __restrict__ tau_I, const float* __restrict__ tau_T,
    long b0s, float* o)
{
    __shared__ float T[2][64 * 68];
    int bid = blockIdx.x;
    int t = threadIdx.x;

    if (bid % 5 != 0) {
        long cid = (long)(bid / 5) * 4 + (bid % 5) - 1;   // 0..4095
        long tid = cid * 256 + t;
        {
            const nf4* s = (const nf4*)(s_I + b0s);
            float* d = o + b0s;
            long n4 = (NSTATE - b0s) / 4;
            for (long k = tid; k < n4; k += COPY_THREADS) nt_copy4(s, k, d);
        }
        const float* srcs[7] = {s_T, b_I, b_T, u_I, u_T, tau_I, tau_T};
#pragma unroll
        for (int b = 0; b < 7; b++) {
            const nf4* s = (const nf4*)srcs[b];
            float* d = o + (long)(b + 1) * NSTATE;
            for (long k = tid; k < NSTATE / 4; k += COPY_THREADS) nt_copy4(s, k, d);
        }
        return;
    }

    int gid = bid / 5;                 // 0..1023
    int by = gid >> 5, bx = gid & 31;
    int w = t >> 6, l = t & 63;
    int rw = w & 1, cw = w >> 1;
    int h = l >> 5, lc = l & 31;
    int rowbase = by * 128 + rw * 64;
    int colbase = bx * 128 + cw * 64;

    const u16* pAh = Ah + (size_t)(by * 4 + rw * 2) * 8192;
    const u16* pAl = Al + (size_t)(by * 4 + rw * 2) * 8192;
    const u16* pBh = Bh + (size_t)(bx * 4 + cw * 2) * 8192;
    const u16* pBl = Bl + (size_t)(bx * 4 + cw * 2) * 8192;

    f32x16 acc00, acc01, acc10, acc11;
#pragma unroll
    for (int e = 0; e < 16; ++e) { acc00[e] = 0.f; acc01[e] = 0.f; acc10[e] = 0.f; acc11[e] = 0.f; }

    for (int s = 0; s < 16; ++s) {
        int off = s * 512 + l * 8;
        short8 a0h = *(const short8*)(pAh + off);
        short8 a1h = *(const short8*)(pAh + 8192 + off);
        short8 a0l = *(const short8*)(pAl + off);
        short8 a1l = *(const short8*)(pAl + 8192 + off);
        short8 b0h = *(const short8*)(pBh + off);
        short8 b1h = *(const short8*)(pBh + 8192 + off);
        short8 b0l = *(const short8*)(pBl + off);
        short8 b1l = *(const short8*)(pBl + 8192 + off);

        acc00 = MFMA32(a0h, b0h, acc00, 0, 0, 0);
        acc01 = MFMA32(a0h, b1h, acc01, 0, 0, 0);
        acc10 = MFMA32(a1h, b0h, acc10, 0, 0, 0);
        acc11 = MFMA32(a1h, b1h, acc11, 0, 0, 0);
        acc00 = MFMA32(a0h, b0l, acc00, 0, 0, 0);
        acc01 = MFMA32(a0h, b1l, acc01, 0, 0, 0);
        acc10 = MFMA32(a1h, b0l, acc10, 0, 0, 0);
        acc11 = MFMA32(a1h, b1l, acc11, 0, 0, 0);
        acc00 = MFMA32(a0l, b0h, acc00, 0, 0, 0);
        acc01 = MFMA32(a0l, b1h, acc01, 0, 0, 0);
        acc10 = MFMA32(a1l, b0h, acc10, 0, 0, 0);
        acc11 = MFMA32(a1l, b1h, acc11, 0, 0, 0);
    }

#define COLPART(A0, A1, CT) do {                                                   \
        int gc = colbase + (CT) * 32 + lc;                                         \
        float itc = colIT[gc];                                                     \
        float m = -INFINITY;                                                       \
        _Pragma("unroll") for (int e = 0; e < 16; ++e) {                           \
            m = fmaxf(m, (A0)[e]); m = fmaxf(m, (A1)[e]); }                        \
        m = fmaxf(m, __shfl_xor(m, 32));                                           \
        float S1 = 0.f, S2 = 0.f;                                                  \
        _Pragma("unroll") for (int e = 0; e < 16; ++e) {                           \
            float v0 = (A0)[e]; float e0 = __expf((v0 - m) * itc); S1 += e0; S2 += e0 * v0; \
            float v1 = (A1)[e]; float e1 = __expf((v1 - m) * itc); S1 += e1; S2 += e1 * v1; } \
        S1 += __shfl_xor(S1, 32); S2 += __shfl_xor(S2, 32);                        \
        if (h == 0) { int slot = by * 2 + rw;                                      \
            cPM [slot * 4096 + gc] = m;                                            \
            cPS1[slot * 4096 + gc] = S1;                                           \
            cPS2[slot * 4096 + gc] = S2; }                                         \
    } while (0)

    COLPART(acc00, acc10, 0);
    COLPART(acc01, acc11, 1);

#define ROWPART(TB) do {                                                           \
        float* Tb = (TB);                                                          \
        _Pragma("unroll") for (int q = 0; q < 4; ++q) {                            \
            _Pragma("unroll") for (int j = 0; j < 4; ++j) {                        \
                int rr = 8 * q + 4 * h + j;                                        \
                Tb[(rr     ) * 68 + lc     ] = acc00[4 * q + j];                   \
                Tb[(rr     ) * 68 + lc + 32] = acc01[4 * q + j];                   \
                Tb[(rr + 32) * 68 + lc     ] = acc10[4 * q + j];                   \
                Tb[(rr + 32) * 68 + lc + 32] = acc11[4 * q + j]; } }               \
        float itr = rowIT[rowbase + l];                                            \
        float4 vv[16];                                                             \
        _Pragma("unroll") for (int c = 0; c < 16; ++c)                             \
            vv[c] = *(const float4*)&Tb[l * 68 + 4 * c];                           \
        float m = -INFINITY;                                                       \
        _Pragma("unroll") for (int c = 0; c < 16; ++c)                             \
            m = fmaxf(m, fmaxf(fmaxf(vv[c].x, vv[c].y), fmaxf(vv[c].z, vv[c].w))); \
        float S1 = 0.f, S2 = 0.f;                                                  \
        _Pragma("unroll") for (int c = 0; c < 16; ++c) {                           \
            float e0 = __expf((vv[c].x - m) * itr); S1 += e0; S2 += e0 * vv[c].x;  \
            float e1 = __expf((vv[c].y - m) * itr); S1 += e1; S2 += e1 * vv[c].y;  \
            float e2 = __expf((vv[c].z - m) * itr); S1 += e2; S2 += e2 * vv[c].z;  \
            float e3 = __expf((vv[c].w - m) * itr); S1 += e3; S2 += e3 * vv[c].w; }\
        int slot = bx * 2 + cw;                                                    \
        rPM [slot * 4096 + rowbase + l] = m;                                       \
        rPS1[slot * 4096 + rowbase + l] = S1;                                      \
        rPS2[slot * 4096 + rowbase + l] = S2;                                      \
        if (bx == by && rw == cw) diag[rowbase + l] = Tb[l * 68 + l];              \
    } while (0)

    if (w < 2) ROWPART(T[w]);
    __syncthreads();
    if (w >= 2) ROWPART(T[w - 2]);
}

// ---------- K3: merge partials + state math + inline scatter/loss + ticketed scalars ----------
__global__ __launch_bounds__(256) void kmerge(
    const int* __restrict__ ids,
    const float* __restrict__ s_I, const float* __restrict__ b_I,
    const float* __restrict__ u_I, const float* __restrict__ tau_I,
    const float* __restrict__ s_T, const float* __restrict__ b_T,
    const float* __restrict__ u_T, const float* __restrict__ tau_T,
    const float* __restrict__ rowIT, const float* __restrict__ colIT,
    const float* __restrict__ diag,
    const float* __restrict__ rPM, const float* __restrict__ rPS1, const float* __restrict__ rPS2,
    const float* __restrict__ cPM, const float* __restrict__ cPS1, const float* __restrict__ cPS2,
    float* __restrict__ O,
    float* __restrict__ sc_arrs,     // fallback path (o_scat == nullptr)
    float* o_scat,                   // big-ws path: scatter directly into output state
    float* acc4, int* ticket)
{
    int j = blockIdx.x * 256 + threadIdx.x;
    int t = threadIdx.x;
    bool rowside = (j < BDIM);
    int i = rowside ? j : j - BDIM;
    const float* PM  = rowside ? rPM  : cPM;
    const float* PS1 = rowside ? rPS1 : cPS1;
    const float* PS2 = rowside ? rPS2 : cPS2;
    float it = rowside ? rowIT[i] : colIT[i];

    float M = -INFINITY, S1 = 0.f, S2 = 0.f;
    for (int k = 0; k < 64; k++) {
        float m  = PM [k * BDIM + i];
        float s1 = PS1[k * BDIM + i];
        float s2 = PS2[k * BDIM + i];
        float Mn = fmaxf(M, m);
        float ea = __expf((M - Mn) * it);
        float eb = __expf((m - Mn) * it);
        S1 = S1 * ea + s1 * eb;
        S2 = S2 * ea + s2 * eb;
        M = Mn;
    }

    int id = ids[i];
    float tau  = rowside ? tau_I[id] : tau_T[id];
    float oldb = rowside ? b_I[id]   : b_T[id];
    float olds = rowside ? s_I[id]   : s_T[id];
    float oldu = rowside ? u_I[id]   : u_T[id];
    float dg = diag[i];

    float nb = fmaxf(oldb, (M - dg) * it);
    float F  = __expf((M - dg) * it - nb);
    float ed = __expf(-nb);
    float g  = F * S1 - ed;
    float Cs = F * (S2 - dg * S1);

    float s_new = (1.f - C_GAMMA_S) * olds * __expf(oldb - nb) + C_GAMMA_S * g;
    float scl = fmaxf(s_new, C_EPS);
    float loss = Cs / scl;
    float grad = logf(scl) + nb + C_RHO - (Cs / (scl * tau)) * (1.0f / (float)(BDIM - 1));
    float gc = fminf(fmaxf(grad, -C_GRAD_CLIP), C_GRAD_CLIP);
    float u_new = (1.f - C_GAMMA_U) * oldu + C_GAMMA_U * gc;
    float tau_new = fminf(fmaxf(tau - C_ETA * u_new, C_TAU_MIN), C_TAU_MAX);

    int bank0 = rowside ? 0 : 1;   // s, then b(+2), u(+4), tau(+6)
    if (rowside) {
        O[i] = g;
        O[8192 + i] = grad;
    } else {
        O[4096 + i] = g;
        O[12288 + i] = grad;
    }
    if (o_scat) {
        long lid = id;
        o_scat[(long)(bank0 + 0) * NSTATE + lid] = s_new;
        o_scat[(long)(bank0 + 2) * NSTATE + lid] = nb;
        o_scat[(long)(bank0 + 4) * NSTATE + lid] = u_new;
        o_scat[(long)(bank0 + 6) * NSTATE + lid] = tau_new;
    } else {
        int base = rowside ? 0 : 4;
        sc_arrs[(base + 0) * BDIM + i] = s_new;
        sc_arrs[(base + 1) * BDIM + i] = nb;
        sc_arrs[(base + 2) * BDIM + i] = u_new;
        sc_arrs[(base + 3) * BDIM + i] = tau_new;
    }

    // block loss reduction -> one atomic per block (rowside uniform per block)
    __shared__ float red[256];
    red[t] = loss;
    __syncthreads();
    for (int s = 128; s > 0; s >>= 1) {
        if (t < s) red[t] += red[t + s];
        __syncthreads();
    }
    if (t == 0) {
        atomicAdd(&acc4[rowside ? 0 : 1], red[0]);
        __threadfence();
        int old = atomicAdd(ticket, 1);
        if (old == 31) {
            float li = atomicAdd(&acc4[0], 0.f);
            float lt = atomicAdd(&acc4[1], 0.f);
            float invB = 1.0f / (float)BDIM;
            O[16384] = C_ALPHA * (li * invB) + (1.f - C_ALPHA) * (lt * invB);
            O[16385] = acc4[2] * invB;
            O[16386] = acc4[3] * invB;
        }
    }
}

// ---------- K4b (fallback): prefix copy ----------
__global__ __launch_bounds__(256) void kfix(const float* s_I, float* o) {
    long tid = (long)blockIdx.x * 256 + threadIdx.x;
    const nf4* s = (const nf4*)s_I;
    for (long k = tid; k < PREFIX_N4; k += 3584L * 256) nt_copy4(s, k, o);
}

// ---------- K5 (fallback): scatter updated state at ids ----------
__global__ __launch_bounds__(256) void kscat(const int* __restrict__ ids,
                                             const float* __restrict__ sc_arrs,
                                             float* __restrict__ o) {
    int t = blockIdx.x * 256 + threadIdx.x;
    if (t >= BDIM) return;
    long id = ids[t];
    o[0L * NSTATE + id] = sc_arrs[0 * BDIM + t];
    o[1L * NSTATE + id] = sc_arrs[4 * BDIM + t];
    o[2L * NSTATE + id] = sc_arrs[1 * BDIM + t];
    o[3L * NSTATE + id] = sc_arrs[5 * BDIM + t];
    o[4L * NSTATE + id] = sc_arrs[2 * BDIM + t];
    o[5L * NSTATE + id] = sc_arrs[6 * BDIM + t];
    o[6L * NSTATE + id] = sc_arrs[3 * BDIM + t];
    o[7L * NSTATE + id] = sc_arrs[7 * BDIM + t];
}

extern "C" void kernel_launch(void* const* d_in, const int* in_sizes, int n_in,
                              void* d_out, int out_size, void* d_ws, size_t ws_size,
                              hipStream_t stream) {
    const float* zis   = (const float*)d_in[0];
    const float* zjs   = (const float*)d_in[1];
    const int*   ids   = (const int*)d_in[2];
    const float* s_I   = (const float*)d_in[3];
    const float* s_T   = (const float*)d_in[4];
    const float* b_I   = (const float*)d_in[5];
    const float* b_T   = (const float*)d_in[6];
    const float* u_I   = (const float*)d_in[7];
    const float* u_T   = (const float*)d_in[8];
    const float* tau_I = (const float*)d_in[9];
    const float* tau_T = (const float*)d_in[10];
    float* O  = (float*)d_out;
    float* ws = (float*)d_ws;

    // small arrays always in ws
    float* rowIT  = ws;                         // 4096 each
    float* colIT  = ws + 4096;
    float* acc4   = ws + 8192;                  // lossI, lossT, tauIsum, tauTsum
    int*   ticket = (int*)(ws + 8196);
    float* sc_arrs = ws + 16384;                // 8 x 4096 (fallback only)

    const bool bigws = ws_size >= (size_t)16 * 1024 * 1024;

    float *rPM, *rPS1, *rPS2, *cPM, *cPS1, *cPS2, *diag;
    u16 *Ah, *Al, *Bh, *Bl;
    long b0s;
    if (bigws) {
        float* P = ws + 53248;                  // big scratch in d_ws
        rPM  = P;            rPS1 = P + 262144;  rPS2 = P + 524288;
        cPM  = P + 786432;   cPS1 = P + 1048576; cPS2 = P + 1310720;
        diag = P + 1572864;
        Ah = (u16*)(P + 1576960);
        Al = Ah + 1048576; Bh = Al + 1048576; Bl = Bh + 1048576;
        b0s = 0;
    } else {
        float* P = O + 16388;                   // fallback: d_out bank-0 prefix
        rPM  = P;            rPS1 = P + 262144;  rPS2 = P + 524288;
        cPM  = P + 786432;   cPS1 = P + 1048576; cPS2 = P + 1310720;
        diag = P + 1572864;
        Ah = (u16*)(P + 1576960);
        Al = Ah + 1048576; Bh = Al + 1048576; Bl = Bh + 1048576;
        b0s = PREFIX;
    }

    kprep<<<257, 256, 0, stream>>>(zis, zjs, Ah, Al, Bh, Bl,
                                   ids, tau_I, tau_T, rowIT, colIT, acc4, ticket);

    kmain<<<5120, 256, 0, stream>>>(Ah, Al, Bh, Bl, rowIT, colIT,
                                    rPM, rPS1, rPS2, cPM, cPS1, cPS2, diag,
                                    s_I, s_T, b_I, b_T, u_I, u_T, tau_I, tau_T,
                                    b0s, O + 16387);

    kmerge<<<32, 256, 0, stream>>>(ids, s_I, b_I, u_I, tau_I, s_T, b_T, u_T, tau_T,
                                   rowIT, colIT, diag,
                                   rPM, rPS1, rPS2, cPM, cPS1, cPS2,
                                   O, sc_arrs, bigws ? (O + 16387) : nullptr,
                                   acc4, ticket);

    if (!bigws) {
        kfix<<<3584, 256, 0, stream>>>(s_I, O + 16387);
        kscat<<<16, 256, 0, stream>>>(ids, sc_arrs, O + 16387);
    }
}